// Round 7
// baseline (630.501 us; speedup 1.0000x reference)
//
#include <hip/hip_runtime.h>
#include <math.h>

#define EE 1024
#define ROWS_TOT 784   // 576 + 144 + 64
#define WWN 10752      // 768 + 3072 + 6912

typedef __attribute__((ext_vector_type(4))) float f4;
typedef __attribute__((ext_vector_type(4))) float f32x4;
typedef __attribute__((ext_vector_type(8))) __bf16 bf16x8;
typedef __attribute__((ext_vector_type(8))) unsigned short ushort8;

__device__ __forceinline__ unsigned short f2b(float x) {
    unsigned int u = __float_as_uint(x);
    unsigned int r = (u + 0x7fffu + ((u >> 16) & 1u)) >> 16;
    return (unsigned short)r;
}
__device__ __forceinline__ float b2f(unsigned short u) {
    unsigned int v = ((unsigned int)u) << 16;
    return __uint_as_float(v);
}

#define GLOAD16(g, l) __builtin_amdgcn_global_load_lds( \
    (const __attribute__((address_space(1))) unsigned int*)(g), \
    (__attribute__((address_space(3))) unsigned int*)(l), 16, 0, 0)

// LDS bank-conflict swizzle (both-sides involution): 64B rows = 4 x 16B segs;
// stored seg s of row r holds global seg s ^ ((r>>1)&3). Staging pre-swizzles
// the GLOBAL source (global_load_lds dest stays linear); reads swizzle the slot.

// ---------------------------------------------------------------------------
// 256x256 value GEMM, 8 waves (2m x 4n), per-wave 128x64 (8x4 frags), BK=32,
// 2-phase double-buffered LDS (64KB). A rows gathered from FEAT [B*576,768]
// with per-level remap; B = WW slice (row stride WWN, col offset per level).
// SPLIT: write fp32 partial for K-chunk blockIdx.z; else bf16 VAL (+bias).
// ---------------------------------------------------------------------------
template<int MODE, bool SPLIT>
__global__ __launch_bounds__(512, 2) void gemm256(
    const unsigned short* __restrict__ FEAT, const unsigned short* __restrict__ WW,
    const float* __restrict__ bias, void* __restrict__ outp,
    int ktCount, int partStride)
{
    constexpr int gw = (MODE == 1) ? 24 : (MODE == 2 ? 12 : 8);
    constexpr int Rl = gw * gw;                                   // 576/144/64
    constexpr int colOff = (MODE == 1) ? 0 : (MODE == 2 ? 768 : 3840);
    constexpr int rowOff = (MODE == 1) ? 0 : (MODE == 2 ? 576 : 720);

    __shared__ unsigned short As[2][256 * 32];   // 16KB each
    __shared__ unsigned short Bs[2][256 * 32];

    const int t = threadIdx.x;
    const int lane = t & 63;
    const int w = t >> 6;                // 0..7
    const int wm = w >> 2;               // 0..1  (128-row half)
    const int wn = w & 3;                // 0..3  (64-col quarter)

    // bijective XCD swizzle over x*y (always %8==0); z untouched
    int nwg = gridDim.x * gridDim.y;
    int bid = blockIdx.y * gridDim.x + blockIdx.x;
    int chunk = nwg >> 3;
    int swz = (bid & 7) * chunk + (bid >> 3);
    int by = swz / gridDim.x, bx = swz % gridDim.x;
    const int m0 = by * 256, n0 = bx * 256;
    const int ktBase = blockIdx.z * ktCount;

    f32x4 acc[8][4] = {};

    // ---- staging roles: per operand, 2 gloads/thread cover 256 rows x 64B ----
    const int srow = lane >> 2;                  // 0..15 row within 16-row group
    const int sseg = lane & 3;                   // stored 16B segment
    const int sgx  = sseg ^ ((lane >> 3) & 3);   // pre-swizzled global segment
    // A source rows (level remap), for gloads g=0,1: lds row = (w*2+g)*16 + srow
    int ga0 = m0 + (w * 2) * 16 + srow;
    int ga1 = ga0 + 16;
    int rbA0, rbA1;
    if (MODE == 1) { rbA0 = ga0; rbA1 = ga1; }
    else {
        int b_ = ga0 / Rl, rl = ga0 - b_ * Rl;
        rbA0 = b_ * 576 + (MODE * (rl / gw)) * 24 + MODE * (rl % gw);
        b_ = ga1 / Rl; rl = ga1 - b_ * Rl;
        rbA1 = b_ * 576 + (MODE * (rl / gw)) * 24 + MODE * (rl % gw);
    }
    const unsigned short* gB0 = WW + (size_t)(n0 + (w * 2) * 16 + srow) * WWN + colOff + sgx * 8;
    const unsigned short* gB1 = gB0 + (size_t)16 * WWN;

    // ---- fragment-read roles ----
    const int fr = lane & 15;
    const int kg = lane >> 4;
    const int kgx = kg ^ ((fr >> 1) & 3);

    auto STAGE = [&](int buf, int ktl) {
        int kt = ktBase + ktl;
        int s = kt / 24;                         // which 768-chunk of K
        int within = (kt - s * 24) * 32;         // + sgx*8 stays within the row
        int add = 0;
        if (MODE == 2)      add = (s >> 1) * 24 + (s & 1);
        else if (MODE == 3) { int di = s / 3; add = di * 24 + (s - 3 * di); }
        GLOAD16(FEAT + (size_t)(rbA0 + add) * 768 + within + sgx * 8, &As[buf][(w * 2 + 0) * 512]);
        GLOAD16(FEAT + (size_t)(rbA1 + add) * 768 + within + sgx * 8, &As[buf][(w * 2 + 1) * 512]);
        GLOAD16(gB0 + (size_t)kt * 32, &Bs[buf][(w * 2 + 0) * 512]);
        GLOAD16(gB1 + (size_t)kt * 32, &Bs[buf][(w * 2 + 1) * 512]);
    };

    const int nt = ktCount;
    int cur = 0;
    STAGE(0, 0);
    __syncthreads();

    for (int tt = 0; tt < nt; ++tt) {
        if (tt + 1 < nt) STAGE(cur ^ 1, tt + 1);
        const unsigned short* rdA = &As[cur][(wm * 128 + fr) * 32 + kgx * 8];
        const unsigned short* rdB = &Bs[cur][(wn * 64 + fr) * 32 + kgx * 8];
        bf16x8 af[8], bf[4];
#pragma unroll
        for (int i = 0; i < 8; ++i) af[i] = *(const bf16x8*)(rdA + i * 512);
#pragma unroll
        for (int j = 0; j < 4; ++j) bf[j] = *(const bf16x8*)(rdB + j * 512);
#pragma unroll
        for (int i = 0; i < 8; ++i)
#pragma unroll
            for (int j = 0; j < 4; ++j)
                acc[i][j] = __builtin_amdgcn_mfma_f32_16x16x32_bf16(af[i], bf[j], acc[i][j], 0, 0, 0);
        if (tt + 1 < nt) { __syncthreads(); cur ^= 1; }
    }

#pragma unroll
    for (int i = 0; i < 8; ++i) {
#pragma unroll
        for (int r = 0; r < 4; ++r) {
            int m = m0 + wm * 128 + i * 16 + kg * 4 + r;   // local level row
#pragma unroll
            for (int j = 0; j < 4; ++j) {
                int n = n0 + wn * 64 + j * 16 + fr;
                if (SPLIT) {
                    float* P = (float*)outp + (size_t)blockIdx.z * partStride;
                    P[(size_t)m * EE + n] = acc[i][j][r];
                } else {
                    int b_o = m / Rl, rl_o = m - b_o * Rl;
                    int crow = b_o * ROWS_TOT + rowOff + rl_o;
                    ((unsigned short*)outp)[(size_t)crow * EE + n] = f2b(acc[i][j][r] + bias[n]);
                }
            }
        }
    }
}

// reduce level-2 split-K partials (2 slices): VAL rows 576..719 per batch
__global__ void reduce2_kernel(const float* __restrict__ P, const float* __restrict__ b2,
                               unsigned short* __restrict__ VAL)
{
    int idx = blockIdx.x * 256 + threadIdx.x;   // 1179648 units of 8 elems
    size_t e0 = (size_t)idx * 8;
    int m = (int)(e0 >> 10);
    int n = (int)(e0 & 1023);
    f4 a0 = *(const f4*)(P + e0);
    f4 a1 = *(const f4*)(P + e0 + 4);
    f4 c0 = *(const f4*)(P + 9437184 + e0);
    f4 c1 = *(const f4*)(P + 9437184 + e0 + 4);
    int crow = (m / 144) * ROWS_TOT + 576 + (m % 144);
    ushort8 o;
#pragma unroll
    for (int i = 0; i < 4; ++i) o[i]     = f2b(a0[i] + c0[i] + b2[n + i]);
#pragma unroll
    for (int i = 0; i < 4; ++i) o[4 + i] = f2b(a1[i] + c1[i] + b2[n + 4 + i]);
    *(ushort8*)(VAL + (size_t)crow * EE + n) = o;
}

// reduce level-3 split-K partials (4 slices): VAL rows 720..783 per batch
__global__ void reduce3_kernel(const float* __restrict__ P, const float* __restrict__ b3,
                               unsigned short* __restrict__ VAL)
{
    int idx = blockIdx.x * 256 + threadIdx.x;   // 524288 units of 8 elems
    size_t e0 = (size_t)idx * 8;
    int m = (int)(e0 >> 10);
    int n = (int)(e0 & 1023);
    f4 s0 = {0.f, 0.f, 0.f, 0.f}, s1 = {0.f, 0.f, 0.f, 0.f};
#pragma unroll
    for (int k = 0; k < 4; ++k) {
        const float* Pz = P + (size_t)k * 4194304;
        f4 a0 = *(const f4*)(Pz + e0);
        f4 a1 = *(const f4*)(Pz + e0 + 4);
#pragma unroll
        for (int i = 0; i < 4; ++i) { s0[i] += a0[i]; s1[i] += a1[i]; }
    }
    int crow = (m >> 6) * ROWS_TOT + 720 + (m & 63);
    ushort8 o;
#pragma unroll
    for (int i = 0; i < 4; ++i) o[i]     = f2b(s0[i] + b3[n + i]);
#pragma unroll
    for (int i = 0; i < 4; ++i) o[4 + i] = f2b(s1[i] + b3[n + 4 + i]);
    *(ushort8*)(VAL + (size_t)crow * EE + n) = o;
}

// ---------------------------------------------------------------------------
// 2-phase double-buffered bf16 MFMA GEMM (128x128, 4 waves) — round-5 proven.
// ---------------------------------------------------------------------------
template<bool OB>
__global__ __launch_bounds__(256) void gemm2(
    const unsigned short* __restrict__ A, const unsigned short* __restrict__ Bw,
    const float* __restrict__ bias, void* __restrict__ Cv,
    int M, int N, int K)
{
    __shared__ unsigned short As[2][128 * 32];
    __shared__ unsigned short Bs[2][128 * 32];
    const int t = threadIdx.x;
    const int lane = t & 63;
    const int w = t >> 6;
    const int wm = w >> 1, wn = w & 1;

    int nwg = gridDim.x * gridDim.y;
    int bid = blockIdx.y * gridDim.x + blockIdx.x;
    int chunk = nwg >> 3;
    int swz = (bid & 7) * chunk + (bid >> 3);
    int by = swz / gridDim.x, bx = swz % gridDim.x;
    const int m0 = by * 128, n0 = bx * 128;

    f32x4 acc[4][4] = {};

    const int sr = lane >> 2;
    const int sc = lane & 3;
    const int scx = sc ^ ((sr >> 1) & 3);
    const unsigned short* gA0 = A + (size_t)(m0 + w * 32 + sr) * K + scx * 8;
    const unsigned short* gA1 = gA0 + (size_t)16 * K;
    const unsigned short* gB0 = Bw + (size_t)(n0 + w * 32 + sr) * K + scx * 8;
    const unsigned short* gB1 = gB0 + (size_t)16 * K;

    const int fr = lane & 15;
    const int kg = lane >> 4;
    const int kgx = kg ^ ((fr >> 1) & 3);

    const int nt = K >> 5;
    int cur = 0;

    auto STAGE = [&](int buf, int k0) {
        GLOAD16(gA0 + k0, &As[buf][w * 1024]);
        GLOAD16(gA1 + k0, &As[buf][w * 1024 + 512]);
        GLOAD16(gB0 + k0, &Bs[buf][w * 1024]);
        GLOAD16(gB1 + k0, &Bs[buf][w * 1024 + 512]);
    };

    STAGE(0, 0);
    __syncthreads();

    for (int tt = 0; tt < nt; ++tt) {
        if (tt + 1 < nt) STAGE(cur ^ 1, (tt + 1) * 32);
        const unsigned short* rdA = &As[cur][(wm * 64 + fr) * 32 + kgx * 8];
        const unsigned short* rdB = &Bs[cur][(wn * 64 + fr) * 32 + kgx * 8];
        bf16x8 af[4], bfr[4];
#pragma unroll
        for (int i = 0; i < 4; ++i) af[i]  = *(const bf16x8*)(rdA + i * 512);
#pragma unroll
        for (int j = 0; j < 4; ++j) bfr[j] = *(const bf16x8*)(rdB + j * 512);
#pragma unroll
        for (int i = 0; i < 4; ++i)
#pragma unroll
            for (int j = 0; j < 4; ++j)
                acc[i][j] = __builtin_amdgcn_mfma_f32_16x16x32_bf16(af[i], bfr[j], acc[i][j], 0, 0, 0);
        if (tt + 1 < nt) { __syncthreads(); cur ^= 1; }
    }

#pragma unroll
    for (int i = 0; i < 4; ++i) {
#pragma unroll
        for (int r = 0; r < 4; ++r) {
            int m = m0 + wm * 64 + i * 16 + kg * 4 + r;
#pragma unroll
            for (int j = 0; j < 4; ++j) {
                int n = n0 + wn * 64 + j * 16 + fr;
                float v = acc[i][j][r];
                if (bias) v += bias[n];
                if (OB) ((unsigned short*)Cv)[(size_t)m * N + n] = f2b(v);
                else    ((float*)Cv)[(size_t)m * N + n] = v;
            }
        }
    }
}

// split-K (z in {0,1}) partial GEMM for the two 4096x1024x1024 epilogue GEMMs
__global__ __launch_bounds__(256) void gemm_pk(
    const unsigned short* __restrict__ A, const unsigned short* __restrict__ Bw,
    float* __restrict__ P)
{
    __shared__ unsigned short As[2][128 * 32];
    __shared__ unsigned short Bs[2][128 * 32];
    const int t = threadIdx.x;
    const int lane = t & 63;
    const int w = t >> 6;
    const int wm = w >> 1, wn = w & 1;
    const int K = 1024;

    int nwg = gridDim.x * gridDim.y;
    int bid = blockIdx.y * gridDim.x + blockIdx.x;
    int chunk = nwg >> 3;
    int swz = (bid & 7) * chunk + (bid >> 3);
    int by = swz / gridDim.x, bx = swz % gridDim.x;
    const int m0 = by * 128, n0 = bx * 128;
    const int kBase = blockIdx.z * 512;

    f32x4 acc[4][4] = {};
    const int sr = lane >> 2;
    const int sc = lane & 3;
    const int scx = sc ^ ((sr >> 1) & 3);
    const unsigned short* gA0 = A + (size_t)(m0 + w * 32 + sr) * K + kBase + scx * 8;
    const unsigned short* gA1 = gA0 + (size_t)16 * K;
    const unsigned short* gB0 = Bw + (size_t)(n0 + w * 32 + sr) * K + kBase + scx * 8;
    const unsigned short* gB1 = gB0 + (size_t)16 * K;
    const int fr = lane & 15;
    const int kg = lane >> 4;
    const int kgx = kg ^ ((fr >> 1) & 3);
    int cur = 0;

    auto STAGE = [&](int buf, int k0) {
        GLOAD16(gA0 + k0, &As[buf][w * 1024]);
        GLOAD16(gA1 + k0, &As[buf][w * 1024 + 512]);
        GLOAD16(gB0 + k0, &Bs[buf][w * 1024]);
        GLOAD16(gB1 + k0, &Bs[buf][w * 1024 + 512]);
    };

    STAGE(0, 0);
    __syncthreads();
    for (int tt = 0; tt < 16; ++tt) {
        if (tt + 1 < 16) STAGE(cur ^ 1, (tt + 1) * 32);
        const unsigned short* rdA = &As[cur][(wm * 64 + fr) * 32 + kgx * 8];
        const unsigned short* rdB = &Bs[cur][(wn * 64 + fr) * 32 + kgx * 8];
        bf16x8 af[4], bfr[4];
#pragma unroll
        for (int i = 0; i < 4; ++i) af[i]  = *(const bf16x8*)(rdA + i * 512);
#pragma unroll
        for (int j = 0; j < 4; ++j) bfr[j] = *(const bf16x8*)(rdB + j * 512);
#pragma unroll
        for (int i = 0; i < 4; ++i)
#pragma unroll
            for (int j = 0; j < 4; ++j)
                acc[i][j] = __builtin_amdgcn_mfma_f32_16x16x32_bf16(af[i], bfr[j], acc[i][j], 0, 0, 0);
        if (tt + 1 < 16) { __syncthreads(); cur ^= 1; }
    }

    float* Pz = P + (size_t)blockIdx.z * (4096 * 1024);
#pragma unroll
    for (int i = 0; i < 4; ++i)
#pragma unroll
        for (int r = 0; r < 4; ++r) {
            int m = m0 + wm * 64 + i * 16 + kg * 4 + r;
#pragma unroll
            for (int j = 0; j < 4; ++j) {
                int n = n0 + wn * 64 + j * 16 + fr;
                Pz[(size_t)m * EE + n] = acc[i][j][r];
            }
        }
}

// fp32 -> bf16 straight copy (count divisible by 2048)
__global__ void f2b_kernel(const float* __restrict__ in, unsigned short* __restrict__ out) {
    size_t i = ((size_t)blockIdx.x * 256 + threadIdx.x) * 8;
    f4 a = *(const f4*)(in + i);
    f4 b = *(const f4*)(in + i + 4);
    ushort8 o;
    o[0] = f2b(a[0]); o[1] = f2b(a[1]); o[2] = f2b(a[2]); o[3] = f2b(a[3]);
    o[4] = f2b(b[0]); o[5] = f2b(b[1]); o[6] = f2b(b[2]); o[7] = f2b(b[3]);
    *(ushort8*)(out + i) = o;
}

// three 1024x1024 weight conversions in one dispatch (512 blocks each)
__global__ void f2b3_kernel(const float* __restrict__ a, unsigned short* __restrict__ oa,
                            const float* __restrict__ b, unsigned short* __restrict__ ob,
                            const float* __restrict__ c, unsigned short* __restrict__ oc) {
    int blk = blockIdx.x;
    const float* in; unsigned short* out;
    if (blk < 512)      { in = a; out = oa; }
    else if (blk < 1024){ in = b; out = ob; blk -= 512; }
    else                { in = c; out = oc; blk -= 1024; }
    size_t i = ((size_t)blk * 256 + threadIdx.x) * 8;
    f4 x = *(const f4*)(in + i);
    f4 y = *(const f4*)(in + i + 4);
    ushort8 o;
    o[0] = f2b(x[0]); o[1] = f2b(x[1]); o[2] = f2b(x[2]); o[3] = f2b(x[3]);
    o[4] = f2b(y[0]); o[5] = f2b(y[1]); o[6] = f2b(y[2]); o[7] = f2b(y[3]);
    *(ushort8*)(out + i) = o;
}

// transpose-convert: in fp32 [R,C] -> out bf16 [C,R]
__global__ void tconv_kernel(const float* __restrict__ in, unsigned short* __restrict__ out,
                             int R, int C) {
    __shared__ float tile[32][33];
    int c0 = blockIdx.x * 32, r0 = blockIdx.y * 32;
    int tx = threadIdx.x & 31, ty = threadIdx.x >> 5;
#pragma unroll
    for (int i = 0; i < 32; i += 8)
        tile[ty + i][tx] = in[(size_t)(r0 + ty + i) * C + c0 + tx];
    __syncthreads();
#pragma unroll
    for (int i = 0; i < 32; i += 8)
        out[(size_t)(c0 + ty + i) * R + r0 + tx] = f2b(tile[tx][ty + i]);
}

// three fused biases in one dispatch: b'[e] = vp_w[e,:]·pb + vp_b[e]
__global__ void fused_bias3_kernel(const float* __restrict__ vp_w, const float* __restrict__ vp_b,
                                   const float* __restrict__ pb1, const float* __restrict__ pb2,
                                   const float* __restrict__ pb3,
                                   float* __restrict__ o1, float* __restrict__ o2, float* __restrict__ o3)
{
    int blk = blockIdx.x;
    const float* pb; float* bout;
    if (blk < 256)      { pb = pb1; bout = o1; }
    else if (blk < 512) { pb = pb2; bout = o2; blk -= 256; }
    else                { pb = pb3; bout = o3; blk -= 512; }
    int e = blk * 4 + (threadIdx.x >> 6);
    int lane = threadIdx.x & 63;
    float s = 0.f;
    for (int k = lane; k < EE; k += 64) s += vp_w[(size_t)e * EE + k] * pb[k];
#pragma unroll
    for (int o = 32; o > 0; o >>= 1) s += __shfl_down(s, o, 64);
    if (lane == 0) bout[e] = s + vp_b[e];
}

// ---------------------------------------------------------------------------
// Query branch (batch-independent), fp64 — DO NOT ALTER (index-snap safety)
// ---------------------------------------------------------------------------
__global__ void rg1_kernel(const float* __restrict__ qe, const float* __restrict__ w,
                           const float* __restrict__ b, double* __restrict__ h0)
{
    int o = blockIdx.x * 4 + (threadIdx.x >> 6);
    int lane = threadIdx.x & 63;
    int q = o >> 10, n = o & 1023;
    double s = 0.0;
    for (int k = lane; k < EE; k += 64)
        s += (double)qe[q * EE + k] * (double)w[(size_t)n * EE + k];
#pragma unroll
    for (int off = 32; off > 0; off >>= 1) s += __shfl_down(s, off, 64);
    if (lane == 0) h0[o] = s + (double)b[n];
}

__global__ void ln_gelu_kernel(const double* __restrict__ h0, const float* __restrict__ g,
                               const float* __restrict__ bb, double* __restrict__ h)
{
    __shared__ double red[256];
    __shared__ double stats[2];
    int q = blockIdx.x, t = threadIdx.x;
    double x[4];
#pragma unroll
    for (int i = 0; i < 4; ++i) x[i] = h0[q * 1024 + t + i * 256];
    double s = x[0] + x[1] + x[2] + x[3];
    red[t] = s; __syncthreads();
    for (int o = 128; o; o >>= 1) { if (t < o) red[t] += red[t + o]; __syncthreads(); }
    if (t == 0) stats[0] = red[0] / 1024.0;
    __syncthreads();
    double mean = stats[0];
    double d = 0.0;
#pragma unroll
    for (int i = 0; i < 4; ++i) { double dd = x[i] - mean; d += dd * dd; }
    red[t] = d; __syncthreads();
    for (int o = 128; o; o >>= 1) { if (t < o) red[t] += red[t + o]; __syncthreads(); }
    if (t == 0) stats[1] = red[0] / 1024.0;
    __syncthreads();
    double inv = 1.0 / sqrt(stats[1] + 1e-5);
#pragma unroll
    for (int i = 0; i < 4; ++i) {
        int c = t + i * 256;
        double y = (x[i] - mean) * inv * (double)g[c] + (double)bb[c];
        h[q * 1024 + c] = y * 0.5 * (1.0 + erf(y * 0.70710678118654752440));
    }
}

__global__ void rp_kernel(const double* __restrict__ h, const float* __restrict__ w2,
                          const float* __restrict__ b2, double* __restrict__ rp)
{
    int o = blockIdx.x * 4 + (threadIdx.x >> 6);
    int lane = threadIdx.x & 63;
    int q = o >> 1, r = o & 1;
    double s = 0.0;
    for (int k = lane; k < EE; k += 64)
        s += h[q * 1024 + k] * (double)w2[r * 1024 + k];
#pragma unroll
    for (int off = 32; off > 0; off >>= 1) s += __shfl_down(s, off, 64);
    if (lane == 0) rp[o] = 1.0 / (1.0 + exp(-(s + (double)b2[r])));
}

__global__ void offidx_kernel(const float* __restrict__ qe, const float* __restrict__ so_w,
                              const float* __restrict__ so_b, const float* __restrict__ aw_w,
                              const float* __restrict__ aw_b, const double* __restrict__ rp,
                              float* __restrict__ awf, int* __restrict__ idxv)
{
    __shared__ double offv[128];
    __shared__ double logit[64];
    int q = blockIdx.x, t = threadIdx.x;
    if (t < 128) {
        double s = 0.0;
        for (int k = 0; k < EE; ++k) s += (double)qe[q * EE + k] * (double)so_w[(size_t)t * EE + k];
        offv[t] = s + (double)so_b[t];
    } else if (t < 192) {
        int n = t - 128;
        double s = 0.0;
        for (int k = 0; k < EE; ++k) s += (double)qe[q * EE + k] * (double)aw_w[(size_t)n * EE + k];
        logit[n] = s + (double)aw_b[n];
    }
    __syncthreads();
    if (t < 64) {
        int hh = t >> 2, p = t & 3;
        double l0 = logit[hh * 4 + 0], l1 = logit[hh * 4 + 1];
        double l2 = logit[hh * 4 + 2], l3 = logit[hh * 4 + 3];
        double m = fmax(fmax(l0, l1), fmax(l2, l3));
        double den = exp(l0 - m) + exp(l1 - m) + exp(l2 - m) + exp(l3 - m);
        awf[(q * 16 + hh) * 4 + p] = (float)(exp(logit[hh * 4 + p] - m) / den);
        const int Wss[3] = {24, 12, 8};
        const int starts[3] = {0, 576, 720};
        double ox = offv[(hh * 4 + p) * 2 + 0], oy = offv[(hh * 4 + p) * 2 + 1];
        double rx = rp[q * 2 + 0], ry = rp[q * 2 + 1];
#pragma unroll
        for (int l = 0; l < 3; ++l) {
            int Ws = Wss[l];
            double sx = rx + ox; sx = sx < 0.0 ? 0.0 : (sx > 1.0 ? 1.0 : sx);
            double sy = ry + oy; sy = sy < 0.0 ? 0.0 : (sy > 1.0 ? 1.0 : sy);
            int x0 = (int)floor(sx * (double)(Ws - 1));
            int y0 = (int)floor(sy * (double)(Ws - 1));
            idxv[((l * 64 + q) * 16 + hh) * 4 + p] = starts[l] + y0 * Ws + x0;
        }
    }
}

// out0[b,q,h,:] = sum_{l,p} aw[q,h,p] * value[b, idx[l,q,h,p], h, :]   (bf16)
__global__ void gather_kernel(const unsigned short* __restrict__ value, const float* __restrict__ awf,
                              const int* __restrict__ idxv, unsigned short* __restrict__ out0)
{
    int unit = blockIdx.x * 4 + (threadIdx.x >> 6);
    int lane = threadIdx.x & 63;
    int b = unit >> 10;
    int rem = unit & 1023;
    int q = rem >> 4, h = rem & 15;
    float acc = 0.f;
#pragma unroll
    for (int l = 0; l < 3; ++l)
#pragma unroll
        for (int p = 0; p < 4; ++p) {
            int row = idxv[((l * 64 + q) * 16 + h) * 4 + p];
            float wgt = awf[(q * 16 + h) * 4 + p];
            acc += wgt * b2f(value[((size_t)(b * ROWS_TOT + row)) * 1024 + h * 64 + lane]);
        }
    out0[((size_t)(b * 64 + q)) * 1024 + h * 64 + lane] = f2b(acc);
}

// LN over (p0 + p1 + op_b), output bf16
__global__ void lnsum_kernel(const float* __restrict__ p0, const float* __restrict__ p1,
                             const float* __restrict__ opb, const float* __restrict__ g,
                             const float* __restrict__ bb, unsigned short* __restrict__ y)
{
    __shared__ float red[256];
    __shared__ float stats[2];
    int r = blockIdx.x, t = threadIdx.x;
    float v[4];
#pragma unroll
    for (int i = 0; i < 4; ++i) {
        int c = t + i * 256;
        size_t ix = (size_t)r * 1024 + c;
        v[i] = p0[ix] + p1[ix] + opb[c];
    }
    float s = v[0] + v[1] + v[2] + v[3];
    red[t] = s; __syncthreads();
    for (int o = 128; o; o >>= 1) { if (t < o) red[t] += red[t + o]; __syncthreads(); }
    if (t == 0) stats[0] = red[0] / 1024.f;
    __syncthreads();
    float mean = stats[0];
    float d = 0.f;
#pragma unroll
    for (int i = 0; i < 4; ++i) { float dd = v[i] - mean; d += dd * dd; }
    red[t] = d; __syncthreads();
    for (int o = 128; o; o >>= 1) { if (t < o) red[t] += red[t + o]; __syncthreads(); }
    if (t == 0) stats[1] = red[0] / 1024.f;
    __syncthreads();
    float inv = 1.f / sqrtf(stats[1] + 1e-5f);
#pragma unroll
    for (int i = 0; i < 4; ++i) {
        int c = t + i * 256;
        y[(size_t)r * 1024 + c] = f2b((v[i] - mean) * inv * g[c] + bb[c]);
    }
}

// out = p0 + p1 + fin_b (fp32)
__global__ void finred_kernel(const float* __restrict__ p0, const float* __restrict__ p1,
                              const float* __restrict__ fb, float* __restrict__ out)
{
    int idx = blockIdx.x * 256 + threadIdx.x;
    size_t e0 = (size_t)idx * 8;
    int n = (int)(e0 & 1023);
    f4 a0 = *(const f4*)(p0 + e0);
    f4 a1 = *(const f4*)(p0 + e0 + 4);
    f4 b0 = *(const f4*)(p1 + e0);
    f4 b1 = *(const f4*)(p1 + e0 + 4);
    f4 o0, o1;
#pragma unroll
    for (int i = 0; i < 4; ++i) { o0[i] = a0[i] + b0[i] + fb[n + i]; o1[i] = a1[i] + b1[i] + fb[n + 4 + i]; }
    *(f4*)(out + e0) = o0;
    *(f4*)(out + e0 + 4) = o1;
}

extern "C" void kernel_launch(void* const* d_in, const int* in_sizes, int n_in,
                              void* d_out, int out_size, void* d_ws, size_t ws_size,
                              hipStream_t stream)
{
    const float* features  = (const float*)d_in[0];
    const float* p1_w      = (const float*)d_in[1];
    const float* p1_b      = (const float*)d_in[2];
    const float* p2_w      = (const float*)d_in[3];
    const float* p2_b      = (const float*)d_in[4];
    const float* p3_w      = (const float*)d_in[5];
    const float* p3_b      = (const float*)d_in[6];
    const float* query_emb = (const float*)d_in[7];
    const float* rg_w1     = (const float*)d_in[8];
    const float* rg_b1     = (const float*)d_in[9];
    const float* rg_g      = (const float*)d_in[10];
    const float* rg_b      = (const float*)d_in[11];
    const float* rg_w2     = (const float*)d_in[12];
    const float* rg_b2     = (const float*)d_in[13];
    const float* so_w      = (const float*)d_in[14];
    const float* so_b      = (const float*)d_in[15];
    const float* aw_w      = (const float*)d_in[16];
    const float* aw_b      = (const float*)d_in[17];
    const float* vp_w      = (const float*)d_in[18];
    const float* vp_b      = (const float*)d_in[19];
    const float* op_w      = (const float*)d_in[20];
    const float* op_b      = (const float*)d_in[21];
    const float* fln_g     = (const float*)d_in[22];
    const float* fln_b     = (const float*)d_in[23];
    const float* fin_w     = (const float*)d_in[24];
    const float* fin_b     = (const float*)d_in[25];
    float* out = (float*)d_out;

    // ---- workspace layout (bytes) ----
    char* p = (char*)d_ws;
    unsigned short* FEAT = (unsigned short*)p; p += 56623104;   // bf16 [B*576,768]
    unsigned short* PT   = (unsigned short*)p; p += 22020096;   // [10752,1024] stacked p_w^T
    unsigned short* WW   = (unsigned short*)p; p += 22020096;   // [1024,10752] fused weights
    unsigned short* VPW  = (unsigned short*)p; p += 2097152;
    unsigned short* VAL  = (unsigned short*)p; p += 102760448;  // value bf16 [64*784,1024]
    float*          SCR  = (float*)p;          p += 79691776;   // partials (L2: 75.5MB max) / POUT / PFIN
    unsigned short* OUT0 = (unsigned short*)p; p += 8388608;
    unsigned short* LNO  = (unsigned short*)p; p += 8388608;
    unsigned short* OPW  = (unsigned short*)p; p += 2097152;
    unsigned short* FINW = (unsigned short*)p; p += 2097152;
    float* b1p  = (float*)p; p += 4096;
    float* b2p  = (float*)p; p += 4096;
    float* b3p  = (float*)p; p += 4096;
    float* awf  = (float*)p; p += 16384;
    int*   idxv = (int*)p;   p += 49152;
    double* h0  = (double*)p; p += 524288;
    double* hb  = (double*)p; p += 524288;
    double* rp  = (double*)p; p += 1024;

    float* PART = SCR;                       // L2: 2 x 9437184 f32; L3: 4 x 4194304 f32 (sequential reuse)
    float* POUT = SCR;                       // 2 x 4194304 f32
    float* PFIN = SCR + 2 * 4194304;

    dim3 blk(256);

    // ---- query branch (fp64, batch-independent) ----
    rg1_kernel<<<16384, blk, 0, stream>>>(query_emb, rg_w1, rg_b1, h0);
    ln_gelu_kernel<<<64, blk, 0, stream>>>(h0, rg_g, rg_b, hb);
    rp_kernel<<<32, blk, 0, stream>>>(hb, rg_w2, rg_b2, rp);
    offidx_kernel<<<64, blk, 0, stream>>>(query_emb, so_w, so_b, aw_w, aw_b, rp, awf, idxv);

    // ---- conversions ----
    f2b3_kernel<<<1536, blk, 0, stream>>>(vp_w, VPW, op_w, OPW, fin_w, FINW);
    f2b_kernel<<<13824, blk, 0, stream>>>(features, FEAT);
    fused_bias3_kernel<<<768, blk, 0, stream>>>(vp_w, vp_b, p1_b, p2_b, p3_b, b1p, b2p, b3p);
    tconv_kernel<<<dim3(24, 32),  blk, 0, stream>>>(p1_w, PT,               1024, 768);
    tconv_kernel<<<dim3(96, 32),  blk, 0, stream>>>(p2_w, PT + 768  * 1024, 1024, 3072);
    tconv_kernel<<<dim3(216, 32), blk, 0, stream>>>(p3_w, PT + 3840 * 1024, 1024, 6912);

    // ---- fused weights: WW[1024,10752] = VPW @ PT^T ----
    gemm2<true><<<dim3(84, 8), blk, 0, stream>>>(VPW, PT, nullptr, WW, 1024, WWN, 1024);

    // ---- value GEMMs, 256x256 8-wave tiles; split-K keeps grids >= 256 ----
    gemm256<1, false><<<dim3(4, 144),   512, 0, stream>>>(FEAT, WW, b1p, VAL, 24, 0);
    gemm256<2, true><<<dim3(4, 36, 2),  512, 0, stream>>>(FEAT, WW, nullptr, PART, 48, 9437184);
    reduce2_kernel<<<4608, blk, 0, stream>>>(PART, b2p, VAL);
    gemm256<3, true><<<dim3(4, 16, 4),  512, 0, stream>>>(FEAT, WW, nullptr, PART, 54, 4194304);
    reduce3_kernel<<<2048, blk, 0, stream>>>(PART, b3p, VAL);

    // ---- deformable gather ----
    gather_kernel<<<16384, blk, 0, stream>>>(VAL, awf, idxv, OUT0);

    // ---- output projection (split-K x2) + LN(sum) + final projection (split-K x2) ----
    gemm_pk<<<dim3(8, 32, 2), blk, 0, stream>>>(OUT0, OPW, POUT);
    lnsum_kernel<<<4096, blk, 0, stream>>>(POUT, POUT + 4194304, op_b, fln_g, fln_b, LNO);
    gemm_pk<<<dim3(8, 32, 2), blk, 0, stream>>>(LNO, FINW, PFIN);
    finred_kernel<<<2048, blk, 0, stream>>>(PFIN, PFIN + 4194304, fin_b, out);
}

// Round 8
// 612.318 us; speedup vs baseline: 1.0297x; 1.0297x over previous
//
#include <hip/hip_runtime.h>
#include <math.h>

#define EE 1024
#define ROWS_TOT 784   // 576 + 144 + 64
#define WWN 10752      // 768 + 3072 + 6912

typedef __attribute__((ext_vector_type(4))) float f4;
typedef __attribute__((ext_vector_type(4))) float f32x4;
typedef __attribute__((ext_vector_type(8))) __bf16 bf16x8;
typedef __attribute__((ext_vector_type(8))) unsigned short ushort8;

__device__ __forceinline__ unsigned short f2b(float x) {
    unsigned int u = __float_as_uint(x);
    unsigned int r = (u + 0x7fffu + ((u >> 16) & 1u)) >> 16;
    return (unsigned short)r;
}
__device__ __forceinline__ float b2f(unsigned short u) {
    unsigned int v = ((unsigned int)u) << 16;
    return __uint_as_float(v);
}

#define GLOAD16(g, l) __builtin_amdgcn_global_load_lds( \
    (const __attribute__((address_space(1))) unsigned int*)(g), \
    (__attribute__((address_space(3))) unsigned int*)(l), 16, 0, 0)

// LDS bank-conflict swizzle (both-sides involution): 64B rows = 4 x 16B segs;
// stored seg s of row r holds global seg s ^ ((r>>1)&3). Staging pre-swizzles
// the GLOBAL source (global_load_lds dest stays linear); reads swizzle the slot.

// ---------------------------------------------------------------------------
// 256x256 value GEMM, 8 waves (2m x 4n), per-wave 128x64 (8x4 frags), BK=32.
// T3+T4+T5 schedule: stage(kt+1) at top of iter kt; boundary-only vmcnt(0)
// (one full iteration of latency cover); 2 MFMA-phases of 16 with raw
// s_barrier + setprio; no per-K-step vmcnt drain.
// ---------------------------------------------------------------------------
template<int MODE, bool SPLIT>
__global__ __launch_bounds__(512, 2) void gemm256(
    const unsigned short* __restrict__ FEAT, const unsigned short* __restrict__ WW,
    const float* __restrict__ bias, void* __restrict__ outp,
    int ktCount, int partStride)
{
    constexpr int gw = (MODE == 1) ? 24 : (MODE == 2 ? 12 : 8);
    constexpr int Rl = gw * gw;                                   // 576/144/64
    constexpr int colOff = (MODE == 1) ? 0 : (MODE == 2 ? 768 : 3840);
    constexpr int rowOff = (MODE == 1) ? 0 : (MODE == 2 ? 576 : 720);

    __shared__ unsigned short As[2][256 * 32];   // 16KB each
    __shared__ unsigned short Bs[2][256 * 32];

    const int t = threadIdx.x;
    const int lane = t & 63;
    const int w = t >> 6;                // 0..7
    const int wm = w >> 2;               // 0..1  (128-row half)
    const int wn = w & 3;                // 0..3  (64-col quarter)

    // bijective XCD swizzle over x*y (always %8==0); z untouched
    int nwg = gridDim.x * gridDim.y;
    int bid = blockIdx.y * gridDim.x + blockIdx.x;
    int chunk = nwg >> 3;
    int swz = (bid & 7) * chunk + (bid >> 3);
    int by = swz / gridDim.x, bx = swz % gridDim.x;
    const int m0 = by * 256, n0 = bx * 256;
    const int ktBase = blockIdx.z * ktCount;

    f32x4 acc[8][4] = {};

    // ---- staging roles: per operand, 2 gloads/thread cover 256 rows x 64B ----
    const int srow = lane >> 2;                  // 0..15 row within 16-row group
    const int sseg = lane & 3;                   // stored 16B segment
    const int sgx  = sseg ^ ((lane >> 3) & 3);   // pre-swizzled global segment
    int ga0 = m0 + (w * 2) * 16 + srow;
    int ga1 = ga0 + 16;
    int rbA0, rbA1;
    if (MODE == 1) { rbA0 = ga0; rbA1 = ga1; }
    else {
        int b_ = ga0 / Rl, rl = ga0 - b_ * Rl;
        rbA0 = b_ * 576 + (MODE * (rl / gw)) * 24 + MODE * (rl % gw);
        b_ = ga1 / Rl; rl = ga1 - b_ * Rl;
        rbA1 = b_ * 576 + (MODE * (rl / gw)) * 24 + MODE * (rl % gw);
    }
    const unsigned short* gB0 = WW + (size_t)(n0 + (w * 2) * 16 + srow) * WWN + colOff + sgx * 8;
    const unsigned short* gB1 = gB0 + (size_t)16 * WWN;

    // ---- fragment-read roles ----
    const int fr = lane & 15;
    const int kg = lane >> 4;
    const int kgx = kg ^ ((fr >> 1) & 3);

    auto STAGE = [&](int buf, int ktl) {
        int kt = ktBase + ktl;
        int s = kt / 24;                         // which 768-chunk of K
        int within = (kt - s * 24) * 32;         // + sgx*8 stays within the row
        int add = 0;
        if (MODE == 2)      add = (s >> 1) * 24 + (s & 1);
        else if (MODE == 3) { int di = s / 3; add = di * 24 + (s - 3 * di); }
        GLOAD16(FEAT + (size_t)(rbA0 + add) * 768 + within + sgx * 8, &As[buf][(w * 2 + 0) * 512]);
        GLOAD16(FEAT + (size_t)(rbA1 + add) * 768 + within + sgx * 8, &As[buf][(w * 2 + 1) * 512]);
        GLOAD16(gB0 + (size_t)kt * 32, &Bs[buf][(w * 2 + 0) * 512]);
        GLOAD16(gB1 + (size_t)kt * 32, &Bs[buf][(w * 2 + 1) * 512]);
    };

    const int nt = ktCount;
    int cur = 0;
    STAGE(0, 0);

    for (int tt = 0; tt < nt; ++tt) {
        // ---- boundary: wait ONLY for the stage issued one full iteration ago
        asm volatile("s_waitcnt vmcnt(0)" ::: "memory");
        __builtin_amdgcn_s_barrier();
        __builtin_amdgcn_sched_barrier(0);

        if (tt + 1 < nt) STAGE(cur ^ 1, tt + 1);        // in flight across phases
        __builtin_amdgcn_sched_barrier(0);

        const unsigned short* rdA = &As[cur][(wm * 128 + fr) * 32 + kgx * 8];
        const unsigned short* rdB = &Bs[cur][(wn * 64 + fr) * 32 + kgx * 8];

        // B held in regs for the whole K-tile
        bf16x8 bf[4];
#pragma unroll
        for (int j = 0; j < 4; ++j) bf[j] = *(const bf16x8*)(rdB + j * 512);

        // ---- phase 0: A frags 0..3, 16 MFMA ----
        {
            bf16x8 af[4];
#pragma unroll
            for (int i = 0; i < 4; ++i) af[i] = *(const bf16x8*)(rdA + i * 512);
            __builtin_amdgcn_s_setprio(1);
#pragma unroll
            for (int i = 0; i < 4; ++i)
#pragma unroll
                for (int j = 0; j < 4; ++j)
                    acc[i][j] = __builtin_amdgcn_mfma_f32_16x16x32_bf16(af[i], bf[j], acc[i][j], 0, 0, 0);
            __builtin_amdgcn_s_setprio(0);
        }
        __builtin_amdgcn_s_barrier();
        __builtin_amdgcn_sched_barrier(0);

        // ---- phase 1: A frags 4..7, 16 MFMA ----
        {
            bf16x8 af[4];
#pragma unroll
            for (int i = 0; i < 4; ++i) af[i] = *(const bf16x8*)(rdA + (4 + i) * 512);
            __builtin_amdgcn_s_setprio(1);
#pragma unroll
            for (int i = 0; i < 4; ++i)
#pragma unroll
                for (int j = 0; j < 4; ++j)
                    acc[4 + i][j] = __builtin_amdgcn_mfma_f32_16x16x32_bf16(af[i], bf[j], acc[4 + i][j], 0, 0, 0);
            __builtin_amdgcn_s_setprio(0);
        }
        cur ^= 1;
    }

#pragma unroll
    for (int i = 0; i < 8; ++i) {
#pragma unroll
        for (int r = 0; r < 4; ++r) {
            int m = m0 + wm * 128 + i * 16 + kg * 4 + r;   // local level row
#pragma unroll
            for (int j = 0; j < 4; ++j) {
                int n = n0 + wn * 64 + j * 16 + fr;
                if (SPLIT) {
                    float* P = (float*)outp + (size_t)blockIdx.z * partStride;
                    P[(size_t)m * EE + n] = acc[i][j][r];
                } else {
                    int b_o = m / Rl, rl_o = m - b_o * Rl;
                    int crow = b_o * ROWS_TOT + rowOff + rl_o;
                    ((unsigned short*)outp)[(size_t)crow * EE + n] = f2b(acc[i][j][r] + bias[n]);
                }
            }
        }
    }
}

// reduce level-2 split-K partials (2 slices): VAL rows 576..719 per batch
__global__ void reduce2_kernel(const float* __restrict__ P, const float* __restrict__ b2,
                               unsigned short* __restrict__ VAL)
{
    int idx = blockIdx.x * 256 + threadIdx.x;   // 1179648 units of 8 elems
    size_t e0 = (size_t)idx * 8;
    int m = (int)(e0 >> 10);
    int n = (int)(e0 & 1023);
    f4 a0 = *(const f4*)(P + e0);
    f4 a1 = *(const f4*)(P + e0 + 4);
    f4 c0 = *(const f4*)(P + 9437184 + e0);
    f4 c1 = *(const f4*)(P + 9437184 + e0 + 4);
    int crow = (m / 144) * ROWS_TOT + 576 + (m % 144);
    ushort8 o;
#pragma unroll
    for (int i = 0; i < 4; ++i) o[i]     = f2b(a0[i] + c0[i] + b2[n + i]);
#pragma unroll
    for (int i = 0; i < 4; ++i) o[4 + i] = f2b(a1[i] + c1[i] + b2[n + 4 + i]);
    *(ushort8*)(VAL + (size_t)crow * EE + n) = o;
}

// reduce level-3 split-K partials (4 slices): VAL rows 720..783 per batch
__global__ void reduce3_kernel(const float* __restrict__ P, const float* __restrict__ b3,
                               unsigned short* __restrict__ VAL)
{
    int idx = blockIdx.x * 256 + threadIdx.x;   // 524288 units of 8 elems
    size_t e0 = (size_t)idx * 8;
    int m = (int)(e0 >> 10);
    int n = (int)(e0 & 1023);
    f4 s0 = {0.f, 0.f, 0.f, 0.f}, s1 = {0.f, 0.f, 0.f, 0.f};
#pragma unroll
    for (int k = 0; k < 4; ++k) {
        const float* Pz = P + (size_t)k * 4194304;
        f4 a0 = *(const f4*)(Pz + e0);
        f4 a1 = *(const f4*)(Pz + e0 + 4);
#pragma unroll
        for (int i = 0; i < 4; ++i) { s0[i] += a0[i]; s1[i] += a1[i]; }
    }
    int crow = (m >> 6) * ROWS_TOT + 720 + (m & 63);
    ushort8 o;
#pragma unroll
    for (int i = 0; i < 4; ++i) o[i]     = f2b(s0[i] + b3[n + i]);
#pragma unroll
    for (int i = 0; i < 4; ++i) o[4 + i] = f2b(s1[i] + b3[n + 4 + i]);
    *(ushort8*)(VAL + (size_t)crow * EE + n) = o;
}

// ---------------------------------------------------------------------------
// 2-phase double-buffered bf16 MFMA GEMM (128x128, 4 waves) — round-5 proven.
// ---------------------------------------------------------------------------
template<bool OB>
__global__ __launch_bounds__(256) void gemm2(
    const unsigned short* __restrict__ A, const unsigned short* __restrict__ Bw,
    const float* __restrict__ bias, void* __restrict__ Cv,
    int M, int N, int K)
{
    __shared__ unsigned short As[2][128 * 32];
    __shared__ unsigned short Bs[2][128 * 32];
    const int t = threadIdx.x;
    const int lane = t & 63;
    const int w = t >> 6;
    const int wm = w >> 1, wn = w & 1;

    int nwg = gridDim.x * gridDim.y;
    int bid = blockIdx.y * gridDim.x + blockIdx.x;
    int chunk = nwg >> 3;
    int swz = (bid & 7) * chunk + (bid >> 3);
    int by = swz / gridDim.x, bx = swz % gridDim.x;
    const int m0 = by * 128, n0 = bx * 128;

    f32x4 acc[4][4] = {};

    const int sr = lane >> 2;
    const int sc = lane & 3;
    const int scx = sc ^ ((sr >> 1) & 3);
    const unsigned short* gA0 = A + (size_t)(m0 + w * 32 + sr) * K + scx * 8;
    const unsigned short* gA1 = gA0 + (size_t)16 * K;
    const unsigned short* gB0 = Bw + (size_t)(n0 + w * 32 + sr) * K + scx * 8;
    const unsigned short* gB1 = gB0 + (size_t)16 * K;

    const int fr = lane & 15;
    const int kg = lane >> 4;
    const int kgx = kg ^ ((fr >> 1) & 3);

    const int nt = K >> 5;
    int cur = 0;

    auto STAGE = [&](int buf, int k0) {
        GLOAD16(gA0 + k0, &As[buf][w * 1024]);
        GLOAD16(gA1 + k0, &As[buf][w * 1024 + 512]);
        GLOAD16(gB0 + k0, &Bs[buf][w * 1024]);
        GLOAD16(gB1 + k0, &Bs[buf][w * 1024 + 512]);
    };

    STAGE(0, 0);
    __syncthreads();

    for (int tt = 0; tt < nt; ++tt) {
        if (tt + 1 < nt) STAGE(cur ^ 1, (tt + 1) * 32);
        const unsigned short* rdA = &As[cur][(wm * 64 + fr) * 32 + kgx * 8];
        const unsigned short* rdB = &Bs[cur][(wn * 64 + fr) * 32 + kgx * 8];
        bf16x8 af[4], bfr[4];
#pragma unroll
        for (int i = 0; i < 4; ++i) af[i]  = *(const bf16x8*)(rdA + i * 512);
#pragma unroll
        for (int j = 0; j < 4; ++j) bfr[j] = *(const bf16x8*)(rdB + j * 512);
#pragma unroll
        for (int i = 0; i < 4; ++i)
#pragma unroll
            for (int j = 0; j < 4; ++j)
                acc[i][j] = __builtin_amdgcn_mfma_f32_16x16x32_bf16(af[i], bfr[j], acc[i][j], 0, 0, 0);
        if (tt + 1 < nt) { __syncthreads(); cur ^= 1; }
    }

#pragma unroll
    for (int i = 0; i < 4; ++i) {
#pragma unroll
        for (int r = 0; r < 4; ++r) {
            int m = m0 + wm * 64 + i * 16 + kg * 4 + r;
#pragma unroll
            for (int j = 0; j < 4; ++j) {
                int n = n0 + wn * 64 + j * 16 + fr;
                float v = acc[i][j][r];
                if (bias) v += bias[n];
                if (OB) ((unsigned short*)Cv)[(size_t)m * N + n] = f2b(v);
                else    ((float*)Cv)[(size_t)m * N + n] = v;
            }
        }
    }
}

// split-K (z in {0,1}) partial GEMM for the two 4096x1024x1024 epilogue GEMMs
__global__ __launch_bounds__(256) void gemm_pk(
    const unsigned short* __restrict__ A, const unsigned short* __restrict__ Bw,
    float* __restrict__ P)
{
    __shared__ unsigned short As[2][128 * 32];
    __shared__ unsigned short Bs[2][128 * 32];
    const int t = threadIdx.x;
    const int lane = t & 63;
    const int w = t >> 6;
    const int wm = w >> 1, wn = w & 1;
    const int K = 1024;

    int nwg = gridDim.x * gridDim.y;
    int bid = blockIdx.y * gridDim.x + blockIdx.x;
    int chunk = nwg >> 3;
    int swz = (bid & 7) * chunk + (bid >> 3);
    int by = swz / gridDim.x, bx = swz % gridDim.x;
    const int m0 = by * 128, n0 = bx * 128;
    const int kBase = blockIdx.z * 512;

    f32x4 acc[4][4] = {};
    const int sr = lane >> 2;
    const int sc = lane & 3;
    const int scx = sc ^ ((sr >> 1) & 3);
    const unsigned short* gA0 = A + (size_t)(m0 + w * 32 + sr) * K + kBase + scx * 8;
    const unsigned short* gA1 = gA0 + (size_t)16 * K;
    const unsigned short* gB0 = Bw + (size_t)(n0 + w * 32 + sr) * K + kBase + scx * 8;
    const unsigned short* gB1 = gB0 + (size_t)16 * K;
    const int fr = lane & 15;
    const int kg = lane >> 4;
    const int kgx = kg ^ ((fr >> 1) & 3);
    int cur = 0;

    auto STAGE = [&](int buf, int k0) {
        GLOAD16(gA0 + k0, &As[buf][w * 1024]);
        GLOAD16(gA1 + k0, &As[buf][w * 1024 + 512]);
        GLOAD16(gB0 + k0, &Bs[buf][w * 1024]);
        GLOAD16(gB1 + k0, &Bs[buf][w * 1024 + 512]);
    };

    STAGE(0, 0);
    __syncthreads();
    for (int tt = 0; tt < 16; ++tt) {
        if (tt + 1 < 16) STAGE(cur ^ 1, (tt + 1) * 32);
        const unsigned short* rdA = &As[cur][(wm * 64 + fr) * 32 + kgx * 8];
        const unsigned short* rdB = &Bs[cur][(wn * 64 + fr) * 32 + kgx * 8];
        bf16x8 af[4], bfr[4];
#pragma unroll
        for (int i = 0; i < 4; ++i) af[i]  = *(const bf16x8*)(rdA + i * 512);
#pragma unroll
        for (int j = 0; j < 4; ++j) bfr[j] = *(const bf16x8*)(rdB + j * 512);
#pragma unroll
        for (int i = 0; i < 4; ++i)
#pragma unroll
            for (int j = 0; j < 4; ++j)
                acc[i][j] = __builtin_amdgcn_mfma_f32_16x16x32_bf16(af[i], bfr[j], acc[i][j], 0, 0, 0);
        if (tt + 1 < 16) { __syncthreads(); cur ^= 1; }
    }

    float* Pz = P + (size_t)blockIdx.z * (4096 * 1024);
#pragma unroll
    for (int i = 0; i < 4; ++i)
#pragma unroll
        for (int r = 0; r < 4; ++r) {
            int m = m0 + wm * 64 + i * 16 + kg * 4 + r;
#pragma unroll
            for (int j = 0; j < 4; ++j) {
                int n = n0 + wn * 64 + j * 16 + fr;
                Pz[(size_t)m * EE + n] = acc[i][j][r];
            }
        }
}

// fp32 -> bf16 straight copy (count divisible by 2048)
__global__ void f2b_kernel(const float* __restrict__ in, unsigned short* __restrict__ out) {
    size_t i = ((size_t)blockIdx.x * 256 + threadIdx.x) * 8;
    f4 a = *(const f4*)(in + i);
    f4 b = *(const f4*)(in + i + 4);
    ushort8 o;
    o[0] = f2b(a[0]); o[1] = f2b(a[1]); o[2] = f2b(a[2]); o[3] = f2b(a[3]);
    o[4] = f2b(b[0]); o[5] = f2b(b[1]); o[6] = f2b(b[2]); o[7] = f2b(b[3]);
    *(ushort8*)(out + i) = o;
}

// three 1024x1024 weight conversions in one dispatch (512 blocks each)
__global__ void f2b3_kernel(const float* __restrict__ a, unsigned short* __restrict__ oa,
                            const float* __restrict__ b, unsigned short* __restrict__ ob,
                            const float* __restrict__ c, unsigned short* __restrict__ oc) {
    int blk = blockIdx.x;
    const float* in; unsigned short* out;
    if (blk < 512)      { in = a; out = oa; }
    else if (blk < 1024){ in = b; out = ob; blk -= 512; }
    else                { in = c; out = oc; blk -= 1024; }
    size_t i = ((size_t)blk * 256 + threadIdx.x) * 8;
    f4 x = *(const f4*)(in + i);
    f4 y = *(const f4*)(in + i + 4);
    ushort8 o;
    o[0] = f2b(x[0]); o[1] = f2b(x[1]); o[2] = f2b(x[2]); o[3] = f2b(x[3]);
    o[4] = f2b(y[0]); o[5] = f2b(y[1]); o[6] = f2b(y[2]); o[7] = f2b(y[3]);
    *(ushort8*)(out + i) = o;
}

// transpose-convert: in fp32 [R,C] -> out bf16 [C,R]
__global__ void tconv_kernel(const float* __restrict__ in, unsigned short* __restrict__ out,
                             int R, int C) {
    __shared__ float tile[32][33];
    int c0 = blockIdx.x * 32, r0 = blockIdx.y * 32;
    int tx = threadIdx.x & 31, ty = threadIdx.x >> 5;
#pragma unroll
    for (int i = 0; i < 32; i += 8)
        tile[ty + i][tx] = in[(size_t)(r0 + ty + i) * C + c0 + tx];
    __syncthreads();
#pragma unroll
    for (int i = 0; i < 32; i += 8)
        out[(size_t)(c0 + ty + i) * R + r0 + tx] = f2b(tile[tx][ty + i]);
}

// three fused biases in one dispatch: b'[e] = vp_w[e,:]·pb + vp_b[e]
__global__ void fused_bias3_kernel(const float* __restrict__ vp_w, const float* __restrict__ vp_b,
                                   const float* __restrict__ pb1, const float* __restrict__ pb2,
                                   const float* __restrict__ pb3,
                                   float* __restrict__ o1, float* __restrict__ o2, float* __restrict__ o3)
{
    int blk = blockIdx.x;
    const float* pb; float* bout;
    if (blk < 256)      { pb = pb1; bout = o1; }
    else if (blk < 512) { pb = pb2; bout = o2; blk -= 256; }
    else                { pb = pb3; bout = o3; blk -= 512; }
    int e = blk * 4 + (threadIdx.x >> 6);
    int lane = threadIdx.x & 63;
    float s = 0.f;
    for (int k = lane; k < EE; k += 64) s += vp_w[(size_t)e * EE + k] * pb[k];
#pragma unroll
    for (int o = 32; o > 0; o >>= 1) s += __shfl_down(s, o, 64);
    if (lane == 0) bout[e] = s + vp_b[e];
}

// ---------------------------------------------------------------------------
// Query branch (batch-independent), fp64 — DO NOT ALTER (index-snap safety)
// ---------------------------------------------------------------------------
__global__ void rg1_kernel(const float* __restrict__ qe, const float* __restrict__ w,
                           const float* __restrict__ b, double* __restrict__ h0)
{
    int o = blockIdx.x * 4 + (threadIdx.x >> 6);
    int lane = threadIdx.x & 63;
    int q = o >> 10, n = o & 1023;
    double s = 0.0;
    for (int k = lane; k < EE; k += 64)
        s += (double)qe[q * EE + k] * (double)w[(size_t)n * EE + k];
#pragma unroll
    for (int off = 32; off > 0; off >>= 1) s += __shfl_down(s, off, 64);
    if (lane == 0) h0[o] = s + (double)b[n];
}

__global__ void ln_gelu_kernel(const double* __restrict__ h0, const float* __restrict__ g,
                               const float* __restrict__ bb, double* __restrict__ h)
{
    __shared__ double red[256];
    __shared__ double stats[2];
    int q = blockIdx.x, t = threadIdx.x;
    double x[4];
#pragma unroll
    for (int i = 0; i < 4; ++i) x[i] = h0[q * 1024 + t + i * 256];
    double s = x[0] + x[1] + x[2] + x[3];
    red[t] = s; __syncthreads();
    for (int o = 128; o; o >>= 1) { if (t < o) red[t] += red[t + o]; __syncthreads(); }
    if (t == 0) stats[0] = red[0] / 1024.0;
    __syncthreads();
    double mean = stats[0];
    double d = 0.0;
#pragma unroll
    for (int i = 0; i < 4; ++i) { double dd = x[i] - mean; d += dd * dd; }
    red[t] = d; __syncthreads();
    for (int o = 128; o; o >>= 1) { if (t < o) red[t] += red[t + o]; __syncthreads(); }
    if (t == 0) stats[1] = red[0] / 1024.0;
    __syncthreads();
    double inv = 1.0 / sqrt(stats[1] + 1e-5);
#pragma unroll
    for (int i = 0; i < 4; ++i) {
        int c = t + i * 256;
        double y = (x[i] - mean) * inv * (double)g[c] + (double)bb[c];
        h[q * 1024 + c] = y * 0.5 * (1.0 + erf(y * 0.70710678118654752440));
    }
}

__global__ void rp_kernel(const double* __restrict__ h, const float* __restrict__ w2,
                          const float* __restrict__ b2, double* __restrict__ rp)
{
    int o = blockIdx.x * 4 + (threadIdx.x >> 6);
    int lane = threadIdx.x & 63;
    int q = o >> 1, r = o & 1;
    double s = 0.0;
    for (int k = lane; k < EE; k += 64)
        s += h[q * 1024 + k] * (double)w2[r * 1024 + k];
#pragma unroll
    for (int off = 32; off > 0; off >>= 1) s += __shfl_down(s, off, 64);
    if (lane == 0) rp[o] = 1.0 / (1.0 + exp(-(s + (double)b2[r])));
}

__global__ void offidx_kernel(const float* __restrict__ qe, const float* __restrict__ so_w,
                              const float* __restrict__ so_b, const float* __restrict__ aw_w,
                              const float* __restrict__ aw_b, const double* __restrict__ rp,
                              float* __restrict__ awf, int* __restrict__ idxv)
{
    __shared__ double offv[128];
    __shared__ double logit[64];
    int q = blockIdx.x, t = threadIdx.x;
    if (t < 128) {
        double s = 0.0;
        for (int k = 0; k < EE; ++k) s += (double)qe[q * EE + k] * (double)so_w[(size_t)t * EE + k];
        offv[t] = s + (double)so_b[t];
    } else if (t < 192) {
        int n = t - 128;
        double s = 0.0;
        for (int k = 0; k < EE; ++k) s += (double)qe[q * EE + k] * (double)aw_w[(size_t)n * EE + k];
        logit[n] = s + (double)aw_b[n];
    }
    __syncthreads();
    if (t < 64) {
        int hh = t >> 2, p = t & 3;
        double l0 = logit[hh * 4 + 0], l1 = logit[hh * 4 + 1];
        double l2 = logit[hh * 4 + 2], l3 = logit[hh * 4 + 3];
        double m = fmax(fmax(l0, l1), fmax(l2, l3));
        double den = exp(l0 - m) + exp(l1 - m) + exp(l2 - m) + exp(l3 - m);
        awf[(q * 16 + hh) * 4 + p] = (float)(exp(logit[hh * 4 + p] - m) / den);
        const int Wss[3] = {24, 12, 8};
        const int starts[3] = {0, 576, 720};
        double ox = offv[(hh * 4 + p) * 2 + 0], oy = offv[(hh * 4 + p) * 2 + 1];
        double rx = rp[q * 2 + 0], ry = rp[q * 2 + 1];
#pragma unroll
        for (int l = 0; l < 3; ++l) {
            int Ws = Wss[l];
            double sx = rx + ox; sx = sx < 0.0 ? 0.0 : (sx > 1.0 ? 1.0 : sx);
            double sy = ry + oy; sy = sy < 0.0 ? 0.0 : (sy > 1.0 ? 1.0 : sy);
            int x0 = (int)floor(sx * (double)(Ws - 1));
            int y0 = (int)floor(sy * (double)(Ws - 1));
            idxv[((l * 64 + q) * 16 + hh) * 4 + p] = starts[l] + y0 * Ws + x0;
        }
    }
}

// out0[b,q,h,:] = sum_{l,p} aw[q,h,p] * value[b, idx[l,q,h,p], h, :]   (bf16)
__global__ void gather_kernel(const unsigned short* __restrict__ value, const float* __restrict__ awf,
                              const int* __restrict__ idxv, unsigned short* __restrict__ out0)
{
    int unit = blockIdx.x * 4 + (threadIdx.x >> 6);
    int lane = threadIdx.x & 63;
    int b = unit >> 10;
    int rem = unit & 1023;
    int q = rem >> 4, h = rem & 15;
    float acc = 0.f;
#pragma unroll
    for (int l = 0; l < 3; ++l)
#pragma unroll
        for (int p = 0; p < 4; ++p) {
            int row = idxv[((l * 64 + q) * 16 + h) * 4 + p];
            float wgt = awf[(q * 16 + h) * 4 + p];
            acc += wgt * b2f(value[((size_t)(b * ROWS_TOT + row)) * 1024 + h * 64 + lane]);
        }
    out0[((size_t)(b * 64 + q)) * 1024 + h * 64 + lane] = f2b(acc);
}

// LN over (p0 + p1 + op_b), output bf16
__global__ void lnsum_kernel(const float* __restrict__ p0, const float* __restrict__ p1,
                             const float* __restrict__ opb, const float* __restrict__ g,
                             const float* __restrict__ bb, unsigned short* __restrict__ y)
{
    __shared__ float red[256];
    __shared__ float stats[2];
    int r = blockIdx.x, t = threadIdx.x;
    float v[4];
#pragma unroll
    for (int i = 0; i < 4; ++i) {
        int c = t + i * 256;
        size_t ix = (size_t)r * 1024 + c;
        v[i] = p0[ix] + p1[ix] + opb[c];
    }
    float s = v[0] + v[1] + v[2] + v[3];
    red[t] = s; __syncthreads();
    for (int o = 128; o; o >>= 1) { if (t < o) red[t] += red[t + o]; __syncthreads(); }
    if (t == 0) stats[0] = red[0] / 1024.f;
    __syncthreads();
    float mean = stats[0];
    float d = 0.f;
#pragma unroll
    for (int i = 0; i < 4; ++i) { float dd = v[i] - mean; d += dd * dd; }
    red[t] = d; __syncthreads();
    for (int o = 128; o; o >>= 1) { if (t < o) red[t] += red[t + o]; __syncthreads(); }
    if (t == 0) stats[1] = red[0] / 1024.f;
    __syncthreads();
    float inv = 1.f / sqrtf(stats[1] + 1e-5f);
#pragma unroll
    for (int i = 0; i < 4; ++i) {
        int c = t + i * 256;
        y[(size_t)r * 1024 + c] = f2b((v[i] - mean) * inv * g[c] + bb[c]);
    }
}

// out = p0 + p1 + fin_b (fp32)
__global__ void finred_kernel(const float* __restrict__ p0, const float* __restrict__ p1,
                              const float* __restrict__ fb, float* __restrict__ out)
{
    int idx = blockIdx.x * 256 + threadIdx.x;
    size_t e0 = (size_t)idx * 8;
    int n = (int)(e0 & 1023);
    f4 a0 = *(const f4*)(p0 + e0);
    f4 a1 = *(const f4*)(p0 + e0 + 4);
    f4 b0 = *(const f4*)(p1 + e0);
    f4 b1 = *(const f4*)(p1 + e0 + 4);
    f4 o0, o1;
#pragma unroll
    for (int i = 0; i < 4; ++i) { o0[i] = a0[i] + b0[i] + fb[n + i]; o1[i] = a1[i] + b1[i] + fb[n + 4 + i]; }
    *(f4*)(out + e0) = o0;
    *(f4*)(out + e0 + 4) = o1;
}

extern "C" void kernel_launch(void* const* d_in, const int* in_sizes, int n_in,
                              void* d_out, int out_size, void* d_ws, size_t ws_size,
                              hipStream_t stream)
{
    const float* features  = (const float*)d_in[0];
    const float* p1_w      = (const float*)d_in[1];
    const float* p1_b      = (const float*)d_in[2];
    const float* p2_w      = (const float*)d_in[3];
    const float* p2_b      = (const float*)d_in[4];
    const float* p3_w      = (const float*)d_in[5];
    const float* p3_b      = (const float*)d_in[6];
    const float* query_emb = (const float*)d_in[7];
    const float* rg_w1     = (const float*)d_in[8];
    const float* rg_b1     = (const float*)d_in[9];
    const float* rg_g      = (const float*)d_in[10];
    const float* rg_b      = (const float*)d_in[11];
    const float* rg_w2     = (const float*)d_in[12];
    const float* rg_b2     = (const float*)d_in[13];
    const float* so_w      = (const float*)d_in[14];
    const float* so_b      = (const float*)d_in[15];
    const float* aw_w      = (const float*)d_in[16];
    const float* aw_b      = (const float*)d_in[17];
    const float* vp_w      = (const float*)d_in[18];
    const float* vp_b      = (const float*)d_in[19];
    const float* op_w      = (const float*)d_in[20];
    const float* op_b      = (const float*)d_in[21];
    const float* fln_g     = (const float*)d_in[22];
    const float* fln_b     = (const float*)d_in[23];
    const float* fin_w     = (const float*)d_in[24];
    const float* fin_b     = (const float*)d_in[25];
    float* out = (float*)d_out;

    // ---- workspace layout (bytes) ----
    char* p = (char*)d_ws;
    unsigned short* FEAT = (unsigned short*)p; p += 56623104;   // bf16 [B*576,768]
    unsigned short* PT   = (unsigned short*)p; p += 22020096;   // [10752,1024] stacked p_w^T
    unsigned short* WW   = (unsigned short*)p; p += 22020096;   // [1024,10752] fused weights
    unsigned short* VPW  = (unsigned short*)p; p += 2097152;
    unsigned short* VAL  = (unsigned short*)p; p += 102760448;  // value bf16 [64*784,1024]
    float*          SCR  = (float*)p;          p += 79691776;   // partials / POUT / PFIN
    unsigned short* OUT0 = (unsigned short*)p; p += 8388608;
    unsigned short* LNO  = (unsigned short*)p; p += 8388608;
    unsigned short* OPW  = (unsigned short*)p; p += 2097152;
    unsigned short* FINW = (unsigned short*)p; p += 2097152;
    float* b1p  = (float*)p; p += 4096;
    float* b2p  = (float*)p; p += 4096;
    float* b3p  = (float*)p; p += 4096;
    float* awf  = (float*)p; p += 16384;
    int*   idxv = (int*)p;   p += 49152;
    double* h0  = (double*)p; p += 524288;
    double* hb  = (double*)p; p += 524288;
    double* rp  = (double*)p; p += 1024;

    float* PART = SCR;                       // L2: 2 x 9437184 f32; L3: 4 x 4194304 f32
    float* POUT = SCR;                       // 2 x 4194304 f32
    float* PFIN = SCR + 2 * 4194304;

    dim3 blk(256);

    // ---- query branch (fp64, batch-independent) ----
    rg1_kernel<<<16384, blk, 0, stream>>>(query_emb, rg_w1, rg_b1, h0);
    ln_gelu_kernel<<<64, blk, 0, stream>>>(h0, rg_g, rg_b, hb);
    rp_kernel<<<32, blk, 0, stream>>>(hb, rg_w2, rg_b2, rp);
    offidx_kernel<<<64, blk, 0, stream>>>(query_emb, so_w, so_b, aw_w, aw_b, rp, awf, idxv);

    // ---- conversions ----
    f2b3_kernel<<<1536, blk, 0, stream>>>(vp_w, VPW, op_w, OPW, fin_w, FINW);
    f2b_kernel<<<13824, blk, 0, stream>>>(features, FEAT);
    fused_bias3_kernel<<<768, blk, 0, stream>>>(vp_w, vp_b, p1_b, p2_b, p3_b, b1p, b2p, b3p);
    tconv_kernel<<<dim3(24, 32),  blk, 0, stream>>>(p1_w, PT,               1024, 768);
    tconv_kernel<<<dim3(96, 32),  blk, 0, stream>>>(p2_w, PT + 768  * 1024, 1024, 3072);
    tconv_kernel<<<dim3(216, 32), blk, 0, stream>>>(p3_w, PT + 3840 * 1024, 1024, 6912);

    // ---- fused weights: WW[1024,10752] = VPW @ PT^T ----
    gemm2<true><<<dim3(84, 8), blk, 0, stream>>>(VPW, PT, nullptr, WW, 1024, WWN, 1024);

    // ---- value GEMMs, 256x256 8-wave tiles, T3+T4+T5 schedule ----
    gemm256<1, false><<<dim3(4, 144),   512, 0, stream>>>(FEAT, WW, b1p, VAL, 24, 0);
    gemm256<2, true><<<dim3(4, 36, 2),  512, 0, stream>>>(FEAT, WW, nullptr, PART, 48, 9437184);
    reduce2_kernel<<<4608, blk, 0, stream>>>(PART, b2p, VAL);
    gemm256<3, true><<<dim3(4, 16, 4),  512, 0, stream>>>(FEAT, WW, nullptr, PART, 54, 4194304);
    reduce3_kernel<<<2048, blk, 0, stream>>>(PART, b3p, VAL);

    // ---- deformable gather ----
    gather_kernel<<<16384, blk, 0, stream>>>(VAL, awf, idxv, OUT0);

    // ---- output projection (split-K x2) + LN(sum) + final projection (split-K x2) ----
    gemm_pk<<<dim3(8, 32, 2), blk, 0, stream>>>(OUT0, OPW, POUT);
    lnsum_kernel<<<4096, blk, 0, stream>>>(POUT, POUT + 4194304, op_b, fln_g, fln_b, LNO);
    gemm_pk<<<dim3(8, 32, 2), blk, 0, stream>>>(LNO, FINW, PFIN);
    finred_kernel<<<2048, blk, 0, stream>>>(PFIN, PFIN + 4194304, fin_b, out);
}

// Round 9
// 599.522 us; speedup vs baseline: 1.0517x; 1.0213x over previous
//
#include <hip/hip_runtime.h>
#include <math.h>

#define EE 1024
#define ROWS_TOT 784   // 576 + 144 + 64
#define WWN 10752      // 768 + 3072 + 6912

typedef __attribute__((ext_vector_type(4))) float f4;
typedef __attribute__((ext_vector_type(4))) float f32x4;
typedef __attribute__((ext_vector_type(8))) __bf16 bf16x8;
typedef __attribute__((ext_vector_type(8))) unsigned short ushort8;

__device__ __forceinline__ unsigned short f2b(float x) {
    unsigned int u = __float_as_uint(x);
    unsigned int r = (u + 0x7fffu + ((u >> 16) & 1u)) >> 16;
    return (unsigned short)r;
}
__device__ __forceinline__ float b2f(unsigned short u) {
    unsigned int v = ((unsigned int)u) << 16;
    return __uint_as_float(v);
}

#define GLOAD16(g, l) __builtin_amdgcn_global_load_lds( \
    (const __attribute__((address_space(1))) unsigned int*)(g), \
    (__attribute__((address_space(3))) unsigned int*)(l), 16, 0, 0)

// LDS bank-conflict swizzle (both-sides involution): 64B rows = 4 x 16B segs;
// stored seg s of row r holds global seg s ^ ((r>>1)&3). Staging pre-swizzles
// the GLOBAL source (global_load_lds dest stays linear); reads swizzle the slot.

// ---------------------------------------------------------------------------
// 256x256 value GEMM, 8 waves (2m x 4n), per-wave 128x64 (8x4 frags), BK=32.
// T3+T4+T5 schedule (round-8 proven): stage(kt+1) at top of iter kt;
// boundary-only vmcnt(0); 2 MFMA-phases of 16 with raw s_barrier + setprio.
// SPLIT: write bf16 partial (no bias) for K-chunk blockIdx.z.
// ---------------------------------------------------------------------------
template<int MODE, bool SPLIT>
__global__ __launch_bounds__(512, 2) void gemm256(
    const unsigned short* __restrict__ FEAT, const unsigned short* __restrict__ WW,
    const float* __restrict__ bias, void* __restrict__ outp,
    int ktCount, int partStride)
{
    constexpr int gw = (MODE == 1) ? 24 : (MODE == 2 ? 12 : 8);
    constexpr int Rl = gw * gw;                                   // 576/144/64
    constexpr int colOff = (MODE == 1) ? 0 : (MODE == 2 ? 768 : 3840);
    constexpr int rowOff = (MODE == 1) ? 0 : (MODE == 2 ? 576 : 720);

    __shared__ unsigned short As[2][256 * 32];   // 16KB each
    __shared__ unsigned short Bs[2][256 * 32];

    const int t = threadIdx.x;
    const int lane = t & 63;
    const int w = t >> 6;                // 0..7
    const int wm = w >> 2;               // 0..1  (128-row half)
    const int wn = w & 3;                // 0..3  (64-col quarter)

    // bijective XCD swizzle over x*y (always %8==0); z untouched
    int nwg = gridDim.x * gridDim.y;
    int bid = blockIdx.y * gridDim.x + blockIdx.x;
    int chunk = nwg >> 3;
    int swz = (bid & 7) * chunk + (bid >> 3);
    int by = swz / gridDim.x, bx = swz % gridDim.x;
    const int m0 = by * 256, n0 = bx * 256;
    const int ktBase = blockIdx.z * ktCount;

    f32x4 acc[8][4] = {};

    // ---- staging roles: per operand, 2 gloads/thread cover 256 rows x 64B ----
    const int srow = lane >> 2;                  // 0..15 row within 16-row group
    const int sseg = lane & 3;                   // stored 16B segment
    const int sgx  = sseg ^ ((lane >> 3) & 3);   // pre-swizzled global segment
    int ga0 = m0 + (w * 2) * 16 + srow;
    int ga1 = ga0 + 16;
    int rbA0, rbA1;
    if (MODE == 1) { rbA0 = ga0; rbA1 = ga1; }
    else {
        int b_ = ga0 / Rl, rl = ga0 - b_ * Rl;
        rbA0 = b_ * 576 + (MODE * (rl / gw)) * 24 + MODE * (rl % gw);
        b_ = ga1 / Rl; rl = ga1 - b_ * Rl;
        rbA1 = b_ * 576 + (MODE * (rl / gw)) * 24 + MODE * (rl % gw);
    }
    const unsigned short* gB0 = WW + (size_t)(n0 + (w * 2) * 16 + srow) * WWN + colOff + sgx * 8;
    const unsigned short* gB1 = gB0 + (size_t)16 * WWN;

    // ---- fragment-read roles ----
    const int fr = lane & 15;
    const int kg = lane >> 4;
    const int kgx = kg ^ ((fr >> 1) & 3);

    auto STAGE = [&](int buf, int ktl) {
        int kt = ktBase + ktl;
        int s = kt / 24;                         // which 768-chunk of K
        int within = (kt - s * 24) * 32;         // + sgx*8 stays within the row
        int add = 0;
        if (MODE == 2)      add = (s >> 1) * 24 + (s & 1);
        else if (MODE == 3) { int di = s / 3; add = di * 24 + (s - 3 * di); }
        GLOAD16(FEAT + (size_t)(rbA0 + add) * 768 + within + sgx * 8, &As[buf][(w * 2 + 0) * 512]);
        GLOAD16(FEAT + (size_t)(rbA1 + add) * 768 + within + sgx * 8, &As[buf][(w * 2 + 1) * 512]);
        GLOAD16(gB0 + (size_t)kt * 32, &Bs[buf][(w * 2 + 0) * 512]);
        GLOAD16(gB1 + (size_t)kt * 32, &Bs[buf][(w * 2 + 1) * 512]);
    };

    const int nt = ktCount;
    int cur = 0;
    STAGE(0, 0);

    for (int tt = 0; tt < nt; ++tt) {
        // ---- boundary: wait ONLY for the stage issued one full iteration ago
        asm volatile("s_waitcnt vmcnt(0)" ::: "memory");
        __builtin_amdgcn_s_barrier();
        __builtin_amdgcn_sched_barrier(0);

        if (tt + 1 < nt) STAGE(cur ^ 1, tt + 1);        // in flight across phases
        __builtin_amdgcn_sched_barrier(0);

        const unsigned short* rdA = &As[cur][(wm * 128 + fr) * 32 + kgx * 8];
        const unsigned short* rdB = &Bs[cur][(wn * 64 + fr) * 32 + kgx * 8];

        // B held in regs for the whole K-tile
        bf16x8 bf[4];
#pragma unroll
        for (int j = 0; j < 4; ++j) bf[j] = *(const bf16x8*)(rdB + j * 512);

        // ---- phase 0: A frags 0..3, 16 MFMA ----
        {
            bf16x8 af[4];
#pragma unroll
            for (int i = 0; i < 4; ++i) af[i] = *(const bf16x8*)(rdA + i * 512);
            __builtin_amdgcn_s_setprio(1);
#pragma unroll
            for (int i = 0; i < 4; ++i)
#pragma unroll
                for (int j = 0; j < 4; ++j)
                    acc[i][j] = __builtin_amdgcn_mfma_f32_16x16x32_bf16(af[i], bf[j], acc[i][j], 0, 0, 0);
            __builtin_amdgcn_s_setprio(0);
        }
        __builtin_amdgcn_s_barrier();
        __builtin_amdgcn_sched_barrier(0);

        // ---- phase 1: A frags 4..7, 16 MFMA ----
        {
            bf16x8 af[4];
#pragma unroll
            for (int i = 0; i < 4; ++i) af[i] = *(const bf16x8*)(rdA + (4 + i) * 512);
            __builtin_amdgcn_s_setprio(1);
#pragma unroll
            for (int i = 0; i < 4; ++i)
#pragma unroll
                for (int j = 0; j < 4; ++j)
                    acc[4 + i][j] = __builtin_amdgcn_mfma_f32_16x16x32_bf16(af[i], bf[j], acc[4 + i][j], 0, 0, 0);
            __builtin_amdgcn_s_setprio(0);
        }
        cur ^= 1;
    }

#pragma unroll
    for (int i = 0; i < 8; ++i) {
#pragma unroll
        for (int r = 0; r < 4; ++r) {
            int m = m0 + wm * 128 + i * 16 + kg * 4 + r;   // local level row
#pragma unroll
            for (int j = 0; j < 4; ++j) {
                int n = n0 + wn * 64 + j * 16 + fr;
                if (SPLIT) {
                    unsigned short* P = (unsigned short*)outp + (size_t)blockIdx.z * partStride;
                    P[(size_t)m * EE + n] = f2b(acc[i][j][r]);
                } else {
                    int b_o = m / Rl, rl_o = m - b_o * Rl;
                    int crow = b_o * ROWS_TOT + rowOff + rl_o;
                    ((unsigned short*)outp)[(size_t)crow * EE + n] = f2b(acc[i][j][r] + bias[n]);
                }
            }
        }
    }
}

// reduce level-2 split-K bf16 partials (2 slices): VAL rows 576..719 per batch
__global__ void reduce2_kernel(const unsigned short* __restrict__ P, const float* __restrict__ b2,
                               unsigned short* __restrict__ VAL)
{
    int idx = blockIdx.x * 256 + threadIdx.x;   // 1179648 units of 8 elems
    size_t e0 = (size_t)idx * 8;
    int m = (int)(e0 >> 10);
    int n = (int)(e0 & 1023);
    ushort8 a = *(const ushort8*)(P + e0);
    ushort8 c = *(const ushort8*)(P + 9437184 + e0);
    int crow = (m / 144) * ROWS_TOT + 576 + (m % 144);
    ushort8 o;
#pragma unroll
    for (int i = 0; i < 8; ++i) o[i] = f2b(b2f(a[i]) + b2f(c[i]) + b2[n + i]);
    *(ushort8*)(VAL + (size_t)crow * EE + n) = o;
}

// reduce level-3 split-K bf16 partials (4 slices): VAL rows 720..783 per batch
__global__ void reduce3_kernel(const unsigned short* __restrict__ P, const float* __restrict__ b3,
                               unsigned short* __restrict__ VAL)
{
    int idx = blockIdx.x * 256 + threadIdx.x;   // 524288 units of 8 elems
    size_t e0 = (size_t)idx * 8;
    int m = (int)(e0 >> 10);
    int n = (int)(e0 & 1023);
    float s[8] = {0.f};
#pragma unroll
    for (int k = 0; k < 4; ++k) {
        ushort8 a = *(const ushort8*)(P + (size_t)k * 4194304 + e0);
#pragma unroll
        for (int i = 0; i < 8; ++i) s[i] += b2f(a[i]);
    }
    int crow = (m >> 6) * ROWS_TOT + 720 + (m & 63);
    ushort8 o;
#pragma unroll
    for (int i = 0; i < 8; ++i) o[i] = f2b(s[i] + b3[n + i]);
    *(ushort8*)(VAL + (size_t)crow * EE + n) = o;
}

// ---------------------------------------------------------------------------
// 2-phase double-buffered bf16 MFMA GEMM (128x128, 4 waves) — round-5 proven.
// ---------------------------------------------------------------------------
template<bool OB>
__global__ __launch_bounds__(256) void gemm2(
    const unsigned short* __restrict__ A, const unsigned short* __restrict__ Bw,
    const float* __restrict__ bias, void* __restrict__ Cv,
    int M, int N, int K)
{
    __shared__ unsigned short As[2][128 * 32];
    __shared__ unsigned short Bs[2][128 * 32];
    const int t = threadIdx.x;
    const int lane = t & 63;
    const int w = t >> 6;
    const int wm = w >> 1, wn = w & 1;

    int nwg = gridDim.x * gridDim.y;
    int bid = blockIdx.y * gridDim.x + blockIdx.x;
    int chunk = nwg >> 3;
    int swz = (bid & 7) * chunk + (bid >> 3);
    int by = swz / gridDim.x, bx = swz % gridDim.x;
    const int m0 = by * 128, n0 = bx * 128;

    f32x4 acc[4][4] = {};

    const int sr = lane >> 2;
    const int sc = lane & 3;
    const int scx = sc ^ ((sr >> 1) & 3);
    const unsigned short* gA0 = A + (size_t)(m0 + w * 32 + sr) * K + scx * 8;
    const unsigned short* gA1 = gA0 + (size_t)16 * K;
    const unsigned short* gB0 = Bw + (size_t)(n0 + w * 32 + sr) * K + scx * 8;
    const unsigned short* gB1 = gB0 + (size_t)16 * K;

    const int fr = lane & 15;
    const int kg = lane >> 4;
    const int kgx = kg ^ ((fr >> 1) & 3);

    const int nt = K >> 5;
    int cur = 0;

    auto STAGE = [&](int buf, int k0) {
        GLOAD16(gA0 + k0, &As[buf][w * 1024]);
        GLOAD16(gA1 + k0, &As[buf][w * 1024 + 512]);
        GLOAD16(gB0 + k0, &Bs[buf][w * 1024]);
        GLOAD16(gB1 + k0, &Bs[buf][w * 1024 + 512]);
    };

    STAGE(0, 0);
    __syncthreads();

    for (int tt = 0; tt < nt; ++tt) {
        if (tt + 1 < nt) STAGE(cur ^ 1, (tt + 1) * 32);
        const unsigned short* rdA = &As[cur][(wm * 64 + fr) * 32 + kgx * 8];
        const unsigned short* rdB = &Bs[cur][(wn * 64 + fr) * 32 + kgx * 8];
        bf16x8 af[4], bfr[4];
#pragma unroll
        for (int i = 0; i < 4; ++i) af[i]  = *(const bf16x8*)(rdA + i * 512);
#pragma unroll
        for (int j = 0; j < 4; ++j) bfr[j] = *(const bf16x8*)(rdB + j * 512);
#pragma unroll
        for (int i = 0; i < 4; ++i)
#pragma unroll
            for (int j = 0; j < 4; ++j)
                acc[i][j] = __builtin_amdgcn_mfma_f32_16x16x32_bf16(af[i], bfr[j], acc[i][j], 0, 0, 0);
        if (tt + 1 < nt) { __syncthreads(); cur ^= 1; }
    }

#pragma unroll
    for (int i = 0; i < 4; ++i) {
#pragma unroll
        for (int r = 0; r < 4; ++r) {
            int m = m0 + wm * 64 + i * 16 + kg * 4 + r;
#pragma unroll
            for (int j = 0; j < 4; ++j) {
                int n = n0 + wn * 64 + j * 16 + fr;
                float v = acc[i][j][r];
                if (bias) v += bias[n];
                if (OB) ((unsigned short*)Cv)[(size_t)m * N + n] = f2b(v);
                else    ((float*)Cv)[(size_t)m * N + n] = v;
            }
        }
    }
}

// all fp32->bf16 conversions in one dispatch:
// blocks [0,13824): features; then 512 each for vp_w / op_w / fin_w
__global__ void convall_kernel(const float* __restrict__ feat, unsigned short* __restrict__ FEAT,
                               const float* __restrict__ a, unsigned short* __restrict__ oa,
                               const float* __restrict__ b, unsigned short* __restrict__ ob,
                               const float* __restrict__ c, unsigned short* __restrict__ oc)
{
    int blk = blockIdx.x;
    const float* in; unsigned short* out;
    if (blk < 13824)       { in = feat; out = FEAT; }
    else if (blk < 14336)  { in = a; out = oa; blk -= 13824; }
    else if (blk < 14848)  { in = b; out = ob; blk -= 14336; }
    else                   { in = c; out = oc; blk -= 14848; }
    size_t i = ((size_t)blk * 256 + threadIdx.x) * 8;
    f4 x = *(const f4*)(in + i);
    f4 y = *(const f4*)(in + i + 4);
    ushort8 o;
    o[0] = f2b(x[0]); o[1] = f2b(x[1]); o[2] = f2b(x[2]); o[3] = f2b(x[3]);
    o[4] = f2b(y[0]); o[5] = f2b(y[1]); o[6] = f2b(y[2]); o[7] = f2b(y[3]);
    *(ushort8*)(out + i) = o;
}

// three transpose-converts (R=1024 for all) in one dispatch:
// x-blocks [0,24): p1 (C=768); [24,120): p2 (C=3072); [120,336): p3 (C=6912)
__global__ void tconv3_kernel(const float* __restrict__ p1, const float* __restrict__ p2,
                              const float* __restrict__ p3, unsigned short* __restrict__ PT)
{
    __shared__ float tile[32][33];
    int bx = blockIdx.x;
    const float* in; unsigned short* out; int C;
    if (bx < 24)       { in = p1; out = PT;                C = 768; }
    else if (bx < 120) { in = p2; out = PT + 768  * 1024;  C = 3072; bx -= 24; }
    else               { in = p3; out = PT + 3840 * 1024;  C = 6912; bx -= 120; }
    const int R = 1024;
    int c0 = bx * 32, r0 = blockIdx.y * 32;
    int tx = threadIdx.x & 31, ty = threadIdx.x >> 5;
#pragma unroll
    for (int i = 0; i < 32; i += 8)
        tile[ty + i][tx] = in[(size_t)(r0 + ty + i) * C + c0 + tx];
    __syncthreads();
#pragma unroll
    for (int i = 0; i < 32; i += 8)
        out[(size_t)(c0 + ty + i) * R + r0 + tx] = f2b(tile[tx][ty + i]);
}

// three fused biases in one dispatch: b'[e] = vp_w[e,:]·pb + vp_b[e]
__global__ void fused_bias3_kernel(const float* __restrict__ vp_w, const float* __restrict__ vp_b,
                                   const float* __restrict__ pb1, const float* __restrict__ pb2,
                                   const float* __restrict__ pb3,
                                   float* __restrict__ o1, float* __restrict__ o2, float* __restrict__ o3)
{
    int blk = blockIdx.x;
    const float* pb; float* bout;
    if (blk < 256)      { pb = pb1; bout = o1; }
    else if (blk < 512) { pb = pb2; bout = o2; blk -= 256; }
    else                { pb = pb3; bout = o3; blk -= 512; }
    int e = blk * 4 + (threadIdx.x >> 6);
    int lane = threadIdx.x & 63;
    float s = 0.f;
    for (int k = lane; k < EE; k += 64) s += vp_w[(size_t)e * EE + k] * pb[k];
#pragma unroll
    for (int o = 32; o > 0; o >>= 1) s += __shfl_down(s, o, 64);
    if (lane == 0) bout[e] = s + vp_b[e];
}

// ---------------------------------------------------------------------------
// Query branch (batch-independent), fp64 — DO NOT ALTER (index-snap safety)
// ---------------------------------------------------------------------------
__global__ void rg1_kernel(const float* __restrict__ qe, const float* __restrict__ w,
                           const float* __restrict__ b, double* __restrict__ h0)
{
    int o = blockIdx.x * 4 + (threadIdx.x >> 6);
    int lane = threadIdx.x & 63;
    int q = o >> 10, n = o & 1023;
    double s = 0.0;
    for (int k = lane; k < EE; k += 64)
        s += (double)qe[q * EE + k] * (double)w[(size_t)n * EE + k];
#pragma unroll
    for (int off = 32; off > 0; off >>= 1) s += __shfl_down(s, off, 64);
    if (lane == 0) h0[o] = s + (double)b[n];
}

__global__ void ln_gelu_kernel(const double* __restrict__ h0, const float* __restrict__ g,
                               const float* __restrict__ bb, double* __restrict__ h)
{
    __shared__ double red[256];
    __shared__ double stats[2];
    int q = blockIdx.x, t = threadIdx.x;
    double x[4];
#pragma unroll
    for (int i = 0; i < 4; ++i) x[i] = h0[q * 1024 + t + i * 256];
    double s = x[0] + x[1] + x[2] + x[3];
    red[t] = s; __syncthreads();
    for (int o = 128; o; o >>= 1) { if (t < o) red[t] += red[t + o]; __syncthreads(); }
    if (t == 0) stats[0] = red[0] / 1024.0;
    __syncthreads();
    double mean = stats[0];
    double d = 0.0;
#pragma unroll
    for (int i = 0; i < 4; ++i) { double dd = x[i] - mean; d += dd * dd; }
    red[t] = d; __syncthreads();
    for (int o = 128; o; o >>= 1) { if (t < o) red[t] += red[t + o]; __syncthreads(); }
    if (t == 0) stats[1] = red[0] / 1024.0;
    __syncthreads();
    double inv = 1.0 / sqrt(stats[1] + 1e-5);
#pragma unroll
    for (int i = 0; i < 4; ++i) {
        int c = t + i * 256;
        double y = (x[i] - mean) * inv * (double)g[c] + (double)bb[c];
        h[q * 1024 + c] = y * 0.5 * (1.0 + erf(y * 0.70710678118654752440));
    }
}

__global__ void rp_kernel(const double* __restrict__ h, const float* __restrict__ w2,
                          const float* __restrict__ b2, double* __restrict__ rp)
{
    int o = blockIdx.x * 4 + (threadIdx.x >> 6);
    int lane = threadIdx.x & 63;
    int q = o >> 1, r = o & 1;
    double s = 0.0;
    for (int k = lane; k < EE; k += 64)
        s += h[q * 1024 + k] * (double)w2[r * 1024 + k];
#pragma unroll
    for (int off = 32; off > 0; off >>= 1) s += __shfl_down(s, off, 64);
    if (lane == 0) rp[o] = 1.0 / (1.0 + exp(-(s + (double)b2[r])));
}

__global__ void offidx_kernel(const float* __restrict__ qe, const float* __restrict__ so_w,
                              const float* __restrict__ so_b, const float* __restrict__ aw_w,
                              const float* __restrict__ aw_b, const double* __restrict__ rp,
                              float* __restrict__ awf, int* __restrict__ idxv)
{
    __shared__ double offv[128];
    __shared__ double logit[64];
    int q = blockIdx.x, t = threadIdx.x;
    if (t < 128) {
        double s = 0.0;
        for (int k = 0; k < EE; ++k) s += (double)qe[q * EE + k] * (double)so_w[(size_t)t * EE + k];
        offv[t] = s + (double)so_b[t];
    } else if (t < 192) {
        int n = t - 128;
        double s = 0.0;
        for (int k = 0; k < EE; ++k) s += (double)qe[q * EE + k] * (double)aw_w[(size_t)n * EE + k];
        logit[n] = s + (double)aw_b[n];
    }
    __syncthreads();
    if (t < 64) {
        int hh = t >> 2, p = t & 3;
        double l0 = logit[hh * 4 + 0], l1 = logit[hh * 4 + 1];
        double l2 = logit[hh * 4 + 2], l3 = logit[hh * 4 + 3];
        double m = fmax(fmax(l0, l1), fmax(l2, l3));
        double den = exp(l0 - m) + exp(l1 - m) + exp(l2 - m) + exp(l3 - m);
        awf[(q * 16 + hh) * 4 + p] = (float)(exp(logit[hh * 4 + p] - m) / den);
        const int Wss[3] = {24, 12, 8};
        const int starts[3] = {0, 576, 720};
        double ox = offv[(hh * 4 + p) * 2 + 0], oy = offv[(hh * 4 + p) * 2 + 1];
        double rx = rp[q * 2 + 0], ry = rp[q * 2 + 1];
#pragma unroll
        for (int l = 0; l < 3; ++l) {
            int Ws = Wss[l];
            double sx = rx + ox; sx = sx < 0.0 ? 0.0 : (sx > 1.0 ? 1.0 : sx);
            double sy = ry + oy; sy = sy < 0.0 ? 0.0 : (sy > 1.0 ? 1.0 : sy);
            int x0 = (int)floor(sx * (double)(Ws - 1));
            int y0 = (int)floor(sy * (double)(Ws - 1));
            idxv[((l * 64 + q) * 16 + hh) * 4 + p] = starts[l] + y0 * Ws + x0;
        }
    }
}

// out0[b,q,h,:] = sum_{l,p} aw[q,h,p] * value[b, idx[l,q,h,p], h, :]   (bf16)
__global__ void gather_kernel(const unsigned short* __restrict__ value, const float* __restrict__ awf,
                              const int* __restrict__ idxv, unsigned short* __restrict__ out0)
{
    int unit = blockIdx.x * 4 + (threadIdx.x >> 6);
    int lane = threadIdx.x & 63;
    int b = unit >> 10;
    int rem = unit & 1023;
    int q = rem >> 4, h = rem & 15;
    float acc = 0.f;
#pragma unroll
    for (int l = 0; l < 3; ++l)
#pragma unroll
        for (int p = 0; p < 4; ++p) {
            int row = idxv[((l * 64 + q) * 16 + h) * 4 + p];
            float wgt = awf[(q * 16 + h) * 4 + p];
            acc += wgt * b2f(value[((size_t)(b * ROWS_TOT + row)) * 1024 + h * 64 + lane]);
        }
    out0[((size_t)(b * 64 + q)) * 1024 + h * 64 + lane] = f2b(acc);
}

// fp32 LayerNorm over 1024, output bf16
__global__ void ln_bf16_kernel(const float* __restrict__ x, const float* __restrict__ g,
                               const float* __restrict__ bb, unsigned short* __restrict__ y)
{
    __shared__ float red[256];
    __shared__ float stats[2];
    int r = blockIdx.x, t = threadIdx.x;
    float v[4];
#pragma unroll
    for (int i = 0; i < 4; ++i) v[i] = x[(size_t)r * 1024 + t + i * 256];
    float s = v[0] + v[1] + v[2] + v[3];
    red[t] = s; __syncthreads();
    for (int o = 128; o; o >>= 1) { if (t < o) red[t] += red[t + o]; __syncthreads(); }
    if (t == 0) stats[0] = red[0] / 1024.f;
    __syncthreads();
    float mean = stats[0];
    float d = 0.f;
#pragma unroll
    for (int i = 0; i < 4; ++i) { float dd = v[i] - mean; d += dd * dd; }
    red[t] = d; __syncthreads();
    for (int o = 128; o; o >>= 1) { if (t < o) red[t] += red[t + o]; __syncthreads(); }
    if (t == 0) stats[1] = red[0] / 1024.f;
    __syncthreads();
    float inv = 1.f / sqrtf(stats[1] + 1e-5f);
#pragma unroll
    for (int i = 0; i < 4; ++i) {
        int c = t + i * 256;
        y[(size_t)r * 1024 + c] = f2b((v[i] - mean) * inv * g[c] + bb[c]);
    }
}

extern "C" void kernel_launch(void* const* d_in, const int* in_sizes, int n_in,
                              void* d_out, int out_size, void* d_ws, size_t ws_size,
                              hipStream_t stream)
{
    const float* features  = (const float*)d_in[0];
    const float* p1_w      = (const float*)d_in[1];
    const float* p1_b      = (const float*)d_in[2];
    const float* p2_w      = (const float*)d_in[3];
    const float* p2_b      = (const float*)d_in[4];
    const float* p3_w      = (const float*)d_in[5];
    const float* p3_b      = (const float*)d_in[6];
    const float* query_emb = (const float*)d_in[7];
    const float* rg_w1     = (const float*)d_in[8];
    const float* rg_b1     = (const float*)d_in[9];
    const float* rg_g      = (const float*)d_in[10];
    const float* rg_b      = (const float*)d_in[11];
    const float* rg_w2     = (const float*)d_in[12];
    const float* rg_b2     = (const float*)d_in[13];
    const float* so_w      = (const float*)d_in[14];
    const float* so_b      = (const float*)d_in[15];
    const float* aw_w      = (const float*)d_in[16];
    const float* aw_b      = (const float*)d_in[17];
    const float* vp_w      = (const float*)d_in[18];
    const float* vp_b      = (const float*)d_in[19];
    const float* op_w      = (const float*)d_in[20];
    const float* op_b      = (const float*)d_in[21];
    const float* fln_g     = (const float*)d_in[22];
    const float* fln_b     = (const float*)d_in[23];
    const float* fin_w     = (const float*)d_in[24];
    const float* fin_b     = (const float*)d_in[25];
    float* out = (float*)d_out;

    // ---- workspace layout (bytes) ----
    char* p = (char*)d_ws;
    unsigned short* FEAT = (unsigned short*)p; p += 56623104;   // bf16 [B*576,768]
    unsigned short* PT   = (unsigned short*)p; p += 22020096;   // [10752,1024] stacked p_w^T
    unsigned short* WW   = (unsigned short*)p; p += 22020096;   // [1024,10752] fused weights
    unsigned short* VPW  = (unsigned short*)p; p += 2097152;
    unsigned short* VAL  = (unsigned short*)p; p += 102760448;  // value bf16 [64*784,1024]
    unsigned short* PART = (unsigned short*)p; p += 37748736;   // bf16 partials (L2: 2x9437184)
    float*          OUT1 = (float*)p;          p += 16777216;   // fp32 [4096,1024]
    unsigned short* OUT0 = (unsigned short*)p; p += 8388608;
    unsigned short* LNO  = (unsigned short*)p; p += 8388608;
    unsigned short* OPW  = (unsigned short*)p; p += 2097152;
    unsigned short* FINW = (unsigned short*)p; p += 2097152;
    float* b1p  = (float*)p; p += 4096;
    float* b2p  = (float*)p; p += 4096;
    float* b3p  = (float*)p; p += 4096;
    float* awf  = (float*)p; p += 16384;
    int*   idxv = (int*)p;   p += 49152;
    double* h0  = (double*)p; p += 524288;
    double* hb  = (double*)p; p += 524288;
    double* rp  = (double*)p; p += 1024;

    dim3 blk(256);

    // ---- query branch (fp64, batch-independent) ----
    rg1_kernel<<<16384, blk, 0, stream>>>(query_emb, rg_w1, rg_b1, h0);
    ln_gelu_kernel<<<64, blk, 0, stream>>>(h0, rg_g, rg_b, hb);
    rp_kernel<<<32, blk, 0, stream>>>(hb, rg_w2, rg_b2, rp);
    offidx_kernel<<<64, blk, 0, stream>>>(query_emb, so_w, so_b, aw_w, aw_b, rp, awf, idxv);

    // ---- conversions (merged) ----
    convall_kernel<<<15360, blk, 0, stream>>>(features, FEAT, vp_w, VPW, op_w, OPW, fin_w, FINW);
    fused_bias3_kernel<<<768, blk, 0, stream>>>(vp_w, vp_b, p1_b, p2_b, p3_b, b1p, b2p, b3p);
    tconv3_kernel<<<dim3(336, 32), blk, 0, stream>>>(p1_w, p2_w, p3_w, PT);

    // ---- fused weights: WW[1024,10752] = VPW @ PT^T ----
    gemm2<true><<<dim3(84, 8), blk, 0, stream>>>(VPW, PT, nullptr, WW, 1024, WWN, 1024);

    // ---- value GEMMs, 256x256 8-wave tiles, T3+T4+T5 schedule ----
    gemm256<1, false><<<dim3(4, 144),   512, 0, stream>>>(FEAT, WW, b1p, VAL, 24, 0);
    gemm256<2, true><<<dim3(4, 36, 2),  512, 0, stream>>>(FEAT, WW, nullptr, PART, 48, 9437184);
    reduce2_kernel<<<4608, blk, 0, stream>>>(PART, b2p, VAL);
    gemm256<3, true><<<dim3(4, 16, 4),  512, 0, stream>>>(FEAT, WW, nullptr, PART, 54, 4194304);
    reduce3_kernel<<<2048, blk, 0, stream>>>(PART, b3p, VAL);

    // ---- deformable gather ----
    gather_kernel<<<16384, blk, 0, stream>>>(VAL, awf, idxv, OUT0);

    // ---- output projection + LN + final projection (un-split, direct) ----
    gemm2<false><<<dim3(8, 32), blk, 0, stream>>>(OUT0, OPW, op_b, OUT1, 4096, 1024, 1024);
    ln_bf16_kernel<<<4096, blk, 0, stream>>>(OUT1, fln_g, fln_b, LNO);
    gemm2<false><<<dim3(8, 32), blk, 0, stream>>>(LNO, FINW, fin_b, out, 4096, 1024, 1024);
}

// Round 10
// 556.759 us; speedup vs baseline: 1.1324x; 1.0768x over previous
//
#include <hip/hip_runtime.h>
#include <math.h>

#define EE 1024
#define ROWS_TOT 784   // 576 + 144 + 64
#define WWN 10752      // 768 + 3072 + 6912

typedef __attribute__((ext_vector_type(4))) float f4;
typedef __attribute__((ext_vector_type(4))) float f32x4;
typedef __attribute__((ext_vector_type(8))) __bf16 bf16x8;
typedef __attribute__((ext_vector_type(8))) unsigned short ushort8;

__device__ __forceinline__ unsigned short f2b(float x) {
    unsigned int u = __float_as_uint(x);
    unsigned int r = (u + 0x7fffu + ((u >> 16) & 1u)) >> 16;
    return (unsigned short)r;
}
__device__ __forceinline__ float b2f(unsigned short u) {
    unsigned int v = ((unsigned int)u) << 16;
    return __uint_as_float(v);
}

#define GLOAD16(g, l) __builtin_amdgcn_global_load_lds( \
    (const __attribute__((address_space(1))) unsigned int*)(g), \
    (__attribute__((address_space(3))) unsigned int*)(l), 16, 0, 0)

// ---------------------------------------------------------------------------
// 256x256 value GEMM, BK=64, 8 waves (2m x 4n), per-wave 128x64.
// LDS 128KB (2 x (A 32KB + B 32KB)) -> 1 block/CU. Halves K-step count to
// amortize the measured ~3500cy fixed per-step overhead.
// Swizzle: 128B rows = 8 x 16B slots; slot s of row r holds global chunk
// s ^ (r&7). Staging pre-swizzles the GLOBAL source; reads use
// (kk*4+kg) ^ (fr&7). T3/T4/T5 schedule from round 8 (best measured).
// SPLIT: write bf16 partial (no bias) for K-chunk blockIdx.z.
// ---------------------------------------------------------------------------
template<int MODE, bool SPLIT>
__global__ __launch_bounds__(512, 2) void gemm256(
    const unsigned short* __restrict__ FEAT, const unsigned short* __restrict__ WW,
    const float* __restrict__ bias, void* __restrict__ outp,
    int ktCount, int partStride)
{
    constexpr int gw = (MODE == 1) ? 24 : (MODE == 2 ? 12 : 8);
    constexpr int Rl = gw * gw;                                   // 576/144/64
    constexpr int colOff = (MODE == 1) ? 0 : (MODE == 2 ? 768 : 3840);
    constexpr int rowOff = (MODE == 1) ? 0 : (MODE == 2 ? 576 : 720);

    __shared__ unsigned short As[2][256 * 64];   // 32KB each
    __shared__ unsigned short Bs[2][256 * 64];

    const int t = threadIdx.x;
    const int lane = t & 63;
    const int w = t >> 6;                // 0..7
    const int wm = w >> 2;               // 0..1  (128-row half)
    const int wn = w & 3;                // 0..3  (64-col quarter)

    // bijective XCD swizzle over x*y (always %8==0); z untouched
    int nwg = gridDim.x * gridDim.y;
    int bid = blockIdx.y * gridDim.x + blockIdx.x;
    int chunk = nwg >> 3;
    int swz = (bid & 7) * chunk + (bid >> 3);
    int by = swz / gridDim.x, bx = swz % gridDim.x;
    const int m0 = by * 256, n0 = bx * 256;
    const int ktBase = blockIdx.z * ktCount;

    f32x4 acc[8][4] = {};

    // ---- staging roles: 4 gloads per operand per wave (32 rows x 128B) ----
    const int srow = lane >> 3;                  // 0..7 row within 8-row gload
    const int sseg = lane & 7;                   // stored 16B slot 0..7
    const int sgx  = sseg ^ srow;                // pre-swizzled global chunk
    int rbA[4];
#pragma unroll
    for (int g = 0; g < 4; ++g) {
        int gr = m0 + w * 32 + g * 8 + srow;
        if (MODE == 1) rbA[g] = gr;
        else {
            int b_ = gr / Rl, rl = gr - b_ * Rl;
            rbA[g] = b_ * 576 + (MODE * (rl / gw)) * 24 + MODE * (rl % gw);
        }
    }
    const unsigned short* gBbase = WW + (size_t)(n0 + w * 32 + srow) * WWN + colOff + sgx * 8;

    // ---- fragment-read roles ----
    const int fr = lane & 15;
    const int kg = lane >> 4;
    const int kgx0 = kg ^ (fr & 7);              // kk=0 slot
    const int kgx1 = kgx0 ^ 4;                   // kk=1 slot
    const int aOff0 = (wm * 128 + fr) * 64 + kgx0 * 8;
    const int aOff1 = (wm * 128 + fr) * 64 + kgx1 * 8;
    const int bOff0 = (wn * 64 + fr) * 64 + kgx0 * 8;
    const int bOff1 = (wn * 64 + fr) * 64 + kgx1 * 8;

    auto STAGE = [&](int buf, int ktl) {
        int kt = ktBase + ktl;                   // BK=64 tile index
        int s = kt / 12;                         // which 768-chunk of K
        int within = (kt - s * 12) * 64;         // + sgx*8 <= 704+56 < 768
        int add = 0;
        if (MODE == 2)      add = (s >> 1) * 24 + (s & 1);
        else if (MODE == 3) { int di = s / 3; add = di * 24 + (s - 3 * di); }
#pragma unroll
        for (int g = 0; g < 4; ++g)
            GLOAD16(FEAT + (size_t)(rbA[g] + add) * 768 + within + sgx * 8,
                    &As[buf][(w * 32 + g * 8) * 64]);
#pragma unroll
        for (int g = 0; g < 4; ++g)
            GLOAD16(gBbase + (size_t)(g * 8) * WWN + (size_t)kt * 64,
                    &Bs[buf][(w * 32 + g * 8) * 64]);
    };

    const int nt = ktCount;
    int cur = 0;
    STAGE(0, 0);

    for (int tt = 0; tt < nt; ++tt) {
        // boundary: wait only for the stage issued one full iteration ago
        asm volatile("s_waitcnt vmcnt(0)" ::: "memory");
        __builtin_amdgcn_s_barrier();
        __builtin_amdgcn_sched_barrier(0);

        if (tt + 1 < nt) STAGE(cur ^ 1, tt + 1);        // in flight across phases
        __builtin_amdgcn_sched_barrier(0);

        // ---- phase kk=0: K elems [0,32) of this 64-K tile, 32 MFMA ----
        {
            bf16x8 bf[4], af[8];
#pragma unroll
            for (int j = 0; j < 4; ++j) bf[j] = *(const bf16x8*)(&Bs[cur][bOff0] + j * 1024);
#pragma unroll
            for (int i = 0; i < 8; ++i) af[i] = *(const bf16x8*)(&As[cur][aOff0] + i * 1024);
            __builtin_amdgcn_s_setprio(1);
#pragma unroll
            for (int i = 0; i < 8; ++i)
#pragma unroll
                for (int j = 0; j < 4; ++j)
                    acc[i][j] = __builtin_amdgcn_mfma_f32_16x16x32_bf16(af[i], bf[j], acc[i][j], 0, 0, 0);
            __builtin_amdgcn_s_setprio(0);
        }
        __builtin_amdgcn_s_barrier();
        __builtin_amdgcn_sched_barrier(0);

        // ---- phase kk=1: K elems [32,64), 32 MFMA ----
        {
            bf16x8 bf[4], af[8];
#pragma unroll
            for (int j = 0; j < 4; ++j) bf[j] = *(const bf16x8*)(&Bs[cur][bOff1] + j * 1024);
#pragma unroll
            for (int i = 0; i < 8; ++i) af[i] = *(const bf16x8*)(&As[cur][aOff1] + i * 1024);
            __builtin_amdgcn_s_setprio(1);
#pragma unroll
            for (int i = 0; i < 8; ++i)
#pragma unroll
                for (int j = 0; j < 4; ++j)
                    acc[i][j] = __builtin_amdgcn_mfma_f32_16x16x32_bf16(af[i], bf[j], acc[i][j], 0, 0, 0);
            __builtin_amdgcn_s_setprio(0);
        }
        cur ^= 1;
    }

#pragma unroll
    for (int i = 0; i < 8; ++i) {
#pragma unroll
        for (int r = 0; r < 4; ++r) {
            int m = m0 + wm * 128 + i * 16 + kg * 4 + r;   // local level row
#pragma unroll
            for (int j = 0; j < 4; ++j) {
                int n = n0 + wn * 64 + j * 16 + fr;
                if (SPLIT) {
                    unsigned short* P = (unsigned short*)outp + (size_t)blockIdx.z * partStride;
                    P[(size_t)m * EE + n] = f2b(acc[i][j][r]);
                } else {
                    int b_o = m / Rl, rl_o = m - b_o * Rl;
                    int crow = b_o * ROWS_TOT + rowOff + rl_o;
                    ((unsigned short*)outp)[(size_t)crow * EE + n] = f2b(acc[i][j][r] + bias[n]);
                }
            }
        }
    }
}

// reduce level-2 split-K bf16 partials (4 slices): VAL rows 576..719 per batch
__global__ void reduce2_kernel(const unsigned short* __restrict__ P, const float* __restrict__ b2,
                               unsigned short* __restrict__ VAL)
{
    int idx = blockIdx.x * 256 + threadIdx.x;   // 1179648 units of 8 elems
    size_t e0 = (size_t)idx * 8;
    int m = (int)(e0 >> 10);
    int n = (int)(e0 & 1023);
    float s[8] = {0.f};
#pragma unroll
    for (int k = 0; k < 4; ++k) {
        ushort8 a = *(const ushort8*)(P + (size_t)k * 9437184 + e0);
#pragma unroll
        for (int i = 0; i < 8; ++i) s[i] += b2f(a[i]);
    }
    int crow = (m / 144) * ROWS_TOT + 576 + (m % 144);
    ushort8 o;
#pragma unroll
    for (int i = 0; i < 8; ++i) o[i] = f2b(s[i] + b2[n + i]);
    *(ushort8*)(VAL + (size_t)crow * EE + n) = o;
}

// reduce level-3 split-K bf16 partials (4 slices): VAL rows 720..783 per batch
__global__ void reduce3_kernel(const unsigned short* __restrict__ P, const float* __restrict__ b3,
                               unsigned short* __restrict__ VAL)
{
    int idx = blockIdx.x * 256 + threadIdx.x;   // 524288 units of 8 elems
    size_t e0 = (size_t)idx * 8;
    int m = (int)(e0 >> 10);
    int n = (int)(e0 & 1023);
    float s[8] = {0.f};
#pragma unroll
    for (int k = 0; k < 4; ++k) {
        ushort8 a = *(const ushort8*)(P + (size_t)k * 4194304 + e0);
#pragma unroll
        for (int i = 0; i < 8; ++i) s[i] += b2f(a[i]);
    }
    int crow = (m >> 6) * ROWS_TOT + 720 + (m & 63);
    ushort8 o;
#pragma unroll
    for (int i = 0; i < 8; ++i) o[i] = f2b(s[i] + b3[n + i]);
    *(ushort8*)(VAL + (size_t)crow * EE + n) = o;
}

// ---------------------------------------------------------------------------
// 2-phase double-buffered bf16 MFMA GEMM (128x128, 4 waves) — round-5 proven.
// ---------------------------------------------------------------------------
template<bool OB>
__global__ __launch_bounds__(256) void gemm2(
    const unsigned short* __restrict__ A, const unsigned short* __restrict__ Bw,
    const float* __restrict__ bias, void* __restrict__ Cv,
    int M, int N, int K)
{
    __shared__ unsigned short As[2][128 * 32];
    __shared__ unsigned short Bs[2][128 * 32];
    const int t = threadIdx.x;
    const int lane = t & 63;
    const int w = t >> 6;
    const int wm = w >> 1, wn = w & 1;

    int nwg = gridDim.x * gridDim.y;
    int bid = blockIdx.y * gridDim.x + blockIdx.x;
    int chunk = nwg >> 3;
    int swz = (bid & 7) * chunk + (bid >> 3);
    int by = swz / gridDim.x, bx = swz % gridDim.x;
    const int m0 = by * 128, n0 = bx * 128;

    f32x4 acc[4][4] = {};

    const int sr = lane >> 2;
    const int sc = lane & 3;
    const int scx = sc ^ ((sr >> 1) & 3);
    const unsigned short* gA0 = A + (size_t)(m0 + w * 32 + sr) * K + scx * 8;
    const unsigned short* gA1 = gA0 + (size_t)16 * K;
    const unsigned short* gB0 = Bw + (size_t)(n0 + w * 32 + sr) * K + scx * 8;
    const unsigned short* gB1 = gB0 + (size_t)16 * K;

    const int fr = lane & 15;
    const int kg = lane >> 4;
    const int kgx = kg ^ ((fr >> 1) & 3);

    const int nt = K >> 5;
    int cur = 0;

    auto STAGE = [&](int buf, int k0) {
        GLOAD16(gA0 + k0, &As[buf][w * 1024]);
        GLOAD16(gA1 + k0, &As[buf][w * 1024 + 512]);
        GLOAD16(gB0 + k0, &Bs[buf][w * 1024]);
        GLOAD16(gB1 + k0, &Bs[buf][w * 1024 + 512]);
    };

    STAGE(0, 0);
    __syncthreads();

    for (int tt = 0; tt < nt; ++tt) {
        if (tt + 1 < nt) STAGE(cur ^ 1, (tt + 1) * 32);
        const unsigned short* rdA = &As[cur][(wm * 64 + fr) * 32 + kgx * 8];
        const unsigned short* rdB = &Bs[cur][(wn * 64 + fr) * 32 + kgx * 8];
        bf16x8 af[4], bfr[4];
#pragma unroll
        for (int i = 0; i < 4; ++i) af[i]  = *(const bf16x8*)(rdA + i * 512);
#pragma unroll
        for (int j = 0; j < 4; ++j) bfr[j] = *(const bf16x8*)(rdB + j * 512);
#pragma unroll
        for (int i = 0; i < 4; ++i)
#pragma unroll
            for (int j = 0; j < 4; ++j)
                acc[i][j] = __builtin_amdgcn_mfma_f32_16x16x32_bf16(af[i], bfr[j], acc[i][j], 0, 0, 0);
        if (tt + 1 < nt) { __syncthreads(); cur ^= 1; }
    }

#pragma unroll
    for (int i = 0; i < 4; ++i) {
#pragma unroll
        for (int r = 0; r < 4; ++r) {
            int m = m0 + wm * 64 + i * 16 + kg * 4 + r;
#pragma unroll
            for (int j = 0; j < 4; ++j) {
                int n = n0 + wn * 64 + j * 16 + fr;
                float v = acc[i][j][r];
                if (bias) v += bias[n];
                if (OB) ((unsigned short*)Cv)[(size_t)m * N + n] = f2b(v);
                else    ((float*)Cv)[(size_t)m * N + n] = v;
            }
        }
    }
}

// all fp32->bf16 conversions in one dispatch:
// blocks [0,13824): features; then 512 each for vp_w / op_w / fin_w
__global__ void convall_kernel(const float* __restrict__ feat, unsigned short* __restrict__ FEAT,
                               const float* __restrict__ a, unsigned short* __restrict__ oa,
                               const float* __restrict__ b, unsigned short* __restrict__ ob,
                               const float* __restrict__ c, unsigned short* __restrict__ oc)
{
    int blk = blockIdx.x;
    const float* in; unsigned short* out;
    if (blk < 13824)       { in = feat; out = FEAT; }
    else if (blk < 14336)  { in = a; out = oa; blk -= 13824; }
    else if (blk < 14848)  { in = b; out = ob; blk -= 14336; }
    else                   { in = c; out = oc; blk -= 14848; }
    size_t i = ((size_t)blk * 256 + threadIdx.x) * 8;
    f4 x = *(const f4*)(in + i);
    f4 y = *(const f4*)(in + i + 4);
    ushort8 o;
    o[0] = f2b(x[0]); o[1] = f2b(x[1]); o[2] = f2b(x[2]); o[3] = f2b(x[3]);
    o[4] = f2b(y[0]); o[5] = f2b(y[1]); o[6] = f2b(y[2]); o[7] = f2b(y[3]);
    *(ushort8*)(out + i) = o;
}

// three transpose-converts (R=1024 for all) in one dispatch:
// x-blocks [0,24): p1 (C=768); [24,120): p2 (C=3072); [120,336): p3 (C=6912)
__global__ void tconv3_kernel(const float* __restrict__ p1, const float* __restrict__ p2,
                              const float* __restrict__ p3, unsigned short* __restrict__ PT)
{
    __shared__ float tile[32][33];
    int bx = blockIdx.x;
    const float* in; unsigned short* out; int C;
    if (bx < 24)       { in = p1; out = PT;                C = 768; }
    else if (bx < 120) { in = p2; out = PT + 768  * 1024;  C = 3072; bx -= 24; }
    else               { in = p3; out = PT + 3840 * 1024;  C = 6912; bx -= 120; }
    const int R = 1024;
    int c0 = bx * 32, r0 = blockIdx.y * 32;
    int tx = threadIdx.x & 31, ty = threadIdx.x >> 5;
#pragma unroll
    for (int i = 0; i < 32; i += 8)
        tile[ty + i][tx] = in[(size_t)(r0 + ty + i) * C + c0 + tx];
    __syncthreads();
#pragma unroll
    for (int i = 0; i < 32; i += 8)
        out[(size_t)(c0 + ty + i) * R + r0 + tx] = f2b(tile[tx][ty + i]);
}

// three fused biases in one dispatch: b'[e] = vp_w[e,:]·pb + vp_b[e]
__global__ void fused_bias3_kernel(const float* __restrict__ vp_w, const float* __restrict__ vp_b,
                                   const float* __restrict__ pb1, const float* __restrict__ pb2,
                                   const float* __restrict__ pb3,
                                   float* __restrict__ o1, float* __restrict__ o2, float* __restrict__ o3)
{
    int blk = blockIdx.x;
    const float* pb; float* bout;
    if (blk < 256)      { pb = pb1; bout = o1; }
    else if (blk < 512) { pb = pb2; bout = o2; blk -= 256; }
    else                { pb = pb3; bout = o3; blk -= 512; }
    int e = blk * 4 + (threadIdx.x >> 6);
    int lane = threadIdx.x & 63;
    float s = 0.f;
    for (int k = lane; k < EE; k += 64) s += vp_w[(size_t)e * EE + k] * pb[k];
#pragma unroll
    for (int o = 32; o > 0; o >>= 1) s += __shfl_down(s, o, 64);
    if (lane == 0) bout[e] = s + vp_b[e];
}

// ---------------------------------------------------------------------------
// Query branch (batch-independent), fp64 — DO NOT ALTER (index-snap safety)
// ---------------------------------------------------------------------------
__global__ void rg1_kernel(const float* __restrict__ qe, const float* __restrict__ w,
                           const float* __restrict__ b, double* __restrict__ h0)
{
    int o = blockIdx.x * 4 + (threadIdx.x >> 6);
    int lane = threadIdx.x & 63;
    int q = o >> 10, n = o & 1023;
    double s = 0.0;
    for (int k = lane; k < EE; k += 64)
        s += (double)qe[q * EE + k] * (double)w[(size_t)n * EE + k];
#pragma unroll
    for (int off = 32; off > 0; off >>= 1) s += __shfl_down(s, off, 64);
    if (lane == 0) h0[o] = s + (double)b[n];
}

__global__ void ln_gelu_kernel(const double* __restrict__ h0, const float* __restrict__ g,
                               const float* __restrict__ bb, double* __restrict__ h)
{
    __shared__ double red[256];
    __shared__ double stats[2];
    int q = blockIdx.x, t = threadIdx.x;
    double x[4];
#pragma unroll
    for (int i = 0; i < 4; ++i) x[i] = h0[q * 1024 + t + i * 256];
    double s = x[0] + x[1] + x[2] + x[3];
    red[t] = s; __syncthreads();
    for (int o = 128; o; o >>= 1) { if (t < o) red[t] += red[t + o]; __syncthreads(); }
    if (t == 0) stats[0] = red[0] / 1024.0;
    __syncthreads();
    double mean = stats[0];
    double d = 0.0;
#pragma unroll
    for (int i = 0; i < 4; ++i) { double dd = x[i] - mean; d += dd * dd; }
    red[t] = d; __syncthreads();
    for (int o = 128; o; o >>= 1) { if (t < o) red[t] += red[t + o]; __syncthreads(); }
    if (t == 0) stats[1] = red[0] / 1024.0;
    __syncthreads();
    double inv = 1.0 / sqrt(stats[1] + 1e-5);
#pragma unroll
    for (int i = 0; i < 4; ++i) {
        int c = t + i * 256;
        double y = (x[i] - mean) * inv * (double)g[c] + (double)bb[c];
        h[q * 1024 + c] = y * 0.5 * (1.0 + erf(y * 0.70710678118654752440));
    }
}

__global__ void rp_kernel(const double* __restrict__ h, const float* __restrict__ w2,
                          const float* __restrict__ b2, double* __restrict__ rp)
{
    int o = blockIdx.x * 4 + (threadIdx.x >> 6);
    int lane = threadIdx.x & 63;
    int q = o >> 1, r = o & 1;
    double s = 0.0;
    for (int k = lane; k < EE; k += 64)
        s += h[q * 1024 + k] * (double)w2[r * 1024 + k];
#pragma unroll
    for (int off = 32; off > 0; off >>= 1) s += __shfl_down(s, off, 64);
    if (lane == 0) rp[o] = 1.0 / (1.0 + exp(-(s + (double)b2[r])));
}

__global__ void offidx_kernel(const float* __restrict__ qe, const float* __restrict__ so_w,
                              const float* __restrict__ so_b, const float* __restrict__ aw_w,
                              const float* __restrict__ aw_b, const double* __restrict__ rp,
                              float* __restrict__ awf, int* __restrict__ idxv)
{
    __shared__ double offv[128];
    __shared__ double logit[64];
    int q = blockIdx.x, t = threadIdx.x;
    if (t < 128) {
        double s = 0.0;
        for (int k = 0; k < EE; ++k) s += (double)qe[q * EE + k] * (double)so_w[(size_t)t * EE + k];
        offv[t] = s + (double)so_b[t];
    } else if (t < 192) {
        int n = t - 128;
        double s = 0.0;
        for (int k = 0; k < EE; ++k) s += (double)qe[q * EE + k] * (double)aw_w[(size_t)n * EE + k];
        logit[n] = s + (double)aw_b[n];
    }
    __syncthreads();
    if (t < 64) {
        int hh = t >> 2, p = t & 3;
        double l0 = logit[hh * 4 + 0], l1 = logit[hh * 4 + 1];
        double l2 = logit[hh * 4 + 2], l3 = logit[hh * 4 + 3];
        double m = fmax(fmax(l0, l1), fmax(l2, l3));
        double den = exp(l0 - m) + exp(l1 - m) + exp(l2 - m) + exp(l3 - m);
        awf[(q * 16 + hh) * 4 + p] = (float)(exp(logit[hh * 4 + p] - m) / den);
        const int Wss[3] = {24, 12, 8};
        const int starts[3] = {0, 576, 720};
        double ox = offv[(hh * 4 + p) * 2 + 0], oy = offv[(hh * 4 + p) * 2 + 1];
        double rx = rp[q * 2 + 0], ry = rp[q * 2 + 1];
#pragma unroll
        for (int l = 0; l < 3; ++l) {
            int Ws = Wss[l];
            double sx = rx + ox; sx = sx < 0.0 ? 0.0 : (sx > 1.0 ? 1.0 : sx);
            double sy = ry + oy; sy = sy < 0.0 ? 0.0 : (sy > 1.0 ? 1.0 : sy);
            int x0 = (int)floor(sx * (double)(Ws - 1));
            int y0 = (int)floor(sy * (double)(Ws - 1));
            idxv[((l * 64 + q) * 16 + hh) * 4 + p] = starts[l] + y0 * Ws + x0;
        }
    }
}

// out0[b,q,h,:] = sum_{l,p} aw[q,h,p] * value[b, idx[l,q,h,p], h, :]   (bf16)
__global__ void gather_kernel(const unsigned short* __restrict__ value, const float* __restrict__ awf,
                              const int* __restrict__ idxv, unsigned short* __restrict__ out0)
{
    int unit = blockIdx.x * 4 + (threadIdx.x >> 6);
    int lane = threadIdx.x & 63;
    int b = unit >> 10;
    int rem = unit & 1023;
    int q = rem >> 4, h = rem & 15;
    float acc = 0.f;
#pragma unroll
    for (int l = 0; l < 3; ++l)
#pragma unroll
        for (int p = 0; p < 4; ++p) {
            int row = idxv[((l * 64 + q) * 16 + h) * 4 + p];
            float wgt = awf[(q * 16 + h) * 4 + p];
            acc += wgt * b2f(value[((size_t)(b * ROWS_TOT + row)) * 1024 + h * 64 + lane]);
        }
    out0[((size_t)(b * 64 + q)) * 1024 + h * 64 + lane] = f2b(acc);
}

// fp32 LayerNorm over 1024, output bf16
__global__ void ln_bf16_kernel(const float* __restrict__ x, const float* __restrict__ g,
                               const float* __restrict__ bb, unsigned short* __restrict__ y)
{
    __shared__ float red[256];
    __shared__ float stats[2];
    int r = blockIdx.x, t = threadIdx.x;
    float v[4];
#pragma unroll
    for (int i = 0; i < 4; ++i) v[i] = x[(size_t)r * 1024 + t + i * 256];
    float s = v[0] + v[1] + v[2] + v[3];
    red[t] = s; __syncthreads();
    for (int o = 128; o; o >>= 1) { if (t < o) red[t] += red[t + o]; __syncthreads(); }
    if (t == 0) stats[0] = red[0] / 1024.f;
    __syncthreads();
    float mean = stats[0];
    float d = 0.f;
#pragma unroll
    for (int i = 0; i < 4; ++i) { float dd = v[i] - mean; d += dd * dd; }
    red[t] = d; __syncthreads();
    for (int o = 128; o; o >>= 1) { if (t < o) red[t] += red[t + o]; __syncthreads(); }
    if (t == 0) stats[1] = red[0] / 1024.f;
    __syncthreads();
    float inv = 1.f / sqrtf(stats[1] + 1e-5f);
#pragma unroll
    for (int i = 0; i < 4; ++i) {
        int c = t + i * 256;
        y[(size_t)r * 1024 + c] = f2b((v[i] - mean) * inv * g[c] + bb[c]);
    }
}

extern "C" void kernel_launch(void* const* d_in, const int* in_sizes, int n_in,
                              void* d_out, int out_size, void* d_ws, size_t ws_size,
                              hipStream_t stream)
{
    const float* features  = (const float*)d_in[0];
    const float* p1_w      = (const float*)d_in[1];
    const float* p1_b      = (const float*)d_in[2];
    const float* p2_w      = (const float*)d_in[3];
    const float* p2_b      = (const float*)d_in[4];
    const float* p3_w      = (const float*)d_in[5];
    const float* p3_b      = (const float*)d_in[6];
    const float* query_emb = (const float*)d_in[7];
    const float* rg_w1     = (const float*)d_in[8];
    const float* rg_b1     = (const float*)d_in[9];
    const float* rg_g      = (const float*)d_in[10];
    const float* rg_b      = (const float*)d_in[11];
    const float* rg_w2     = (const float*)d_in[12];
    const float* rg_b2     = (const float*)d_in[13];
    const float* so_w      = (const float*)d_in[14];
    const float* so_b      = (const float*)d_in[15];
    const float* aw_w      = (const float*)d_in[16];
    const float* aw_b      = (const float*)d_in[17];
    const float* vp_w      = (const float*)d_in[18];
    const float* vp_b      = (const float*)d_in[19];
    const float* op_w      = (const float*)d_in[20];
    const float* op_b      = (const float*)d_in[21];
    const float* fln_g     = (const float*)d_in[22];
    const float* fln_b     = (const float*)d_in[23];
    const float* fin_w     = (const float*)d_in[24];
    const float* fin_b     = (const float*)d_in[25];
    float* out = (float*)d_out;

    // ---- workspace layout (bytes) ----
    char* p = (char*)d_ws;
    unsigned short* FEAT = (unsigned short*)p; p += 56623104;   // bf16 [B*576,768]
    unsigned short* PT   = (unsigned short*)p; p += 22020096;   // [10752,1024] stacked p_w^T
    unsigned short* WW   = (unsigned short*)p; p += 22020096;   // [1024,10752] fused weights
    unsigned short* VPW  = (unsigned short*)p; p += 2097152;
    unsigned short* VAL  = (unsigned short*)p; p += 102760448;  // value bf16 [64*784,1024]
    unsigned short* PART = (unsigned short*)p; p += 75497472;   // bf16 partials (L2: 4x9437184)
    float*          OUT1 = (float*)p;          p += 16777216;   // fp32 [4096,1024]
    unsigned short* OUT0 = (unsigned short*)p; p += 8388608;
    unsigned short* LNO  = (unsigned short*)p; p += 8388608;
    unsigned short* OPW  = (unsigned short*)p; p += 2097152;
    unsigned short* FINW = (unsigned short*)p; p += 2097152;
    float* b1p  = (float*)p; p += 4096;
    float* b2p  = (float*)p; p += 4096;
    float* b3p  = (float*)p; p += 4096;
    float* awf  = (float*)p; p += 16384;
    int*   idxv = (int*)p;   p += 49152;
    double* h0  = (double*)p; p += 524288;
    double* hb  = (double*)p; p += 524288;
    double* rp  = (double*)p; p += 1024;

    dim3 blk(256);

    // ---- query branch (fp64, batch-independent) ----
    rg1_kernel<<<16384, blk, 0, stream>>>(query_emb, rg_w1, rg_b1, h0);
    ln_gelu_kernel<<<64, blk, 0, stream>>>(h0, rg_g, rg_b, hb);
    rp_kernel<<<32, blk, 0, stream>>>(hb, rg_w2, rg_b2, rp);
    offidx_kernel<<<64, blk, 0, stream>>>(query_emb, so_w, so_b, aw_w, aw_b, rp, awf, idxv);

    // ---- conversions (merged) ----
    convall_kernel<<<15360, blk, 0, stream>>>(features, FEAT, vp_w, VPW, op_w, OPW, fin_w, FINW);
    fused_bias3_kernel<<<768, blk, 0, stream>>>(vp_w, vp_b, p1_b, p2_b, p3_b, b1p, b2p, b3p);
    tconv3_kernel<<<dim3(336, 32), blk, 0, stream>>>(p1_w, p2_w, p3_w, PT);

    // ---- fused weights: WW[1024,10752] = VPW @ PT^T ----
    gemm2<true><<<dim3(84, 8), blk, 0, stream>>>(VPW, PT, nullptr, WW, 1024, WWN, 1024);

    // ---- value GEMMs, 256x256 BK=64 tiles, T3/T4/T5 schedule ----
    gemm256<1, false><<<dim3(4, 144),    512, 0, stream>>>(FEAT, WW, b1p, VAL, 12, 0);
    gemm256<2, true><<<dim3(4, 36, 4),   512, 0, stream>>>(FEAT, WW, nullptr, PART, 12, 9437184);
    reduce2_kernel<<<4608, blk, 0, stream>>>(PART, b2p, VAL);
    gemm256<3, true><<<dim3(4, 16, 4),   512, 0, stream>>>(FEAT, WW, nullptr, PART, 27, 4194304);
    reduce3_kernel<<<2048, blk, 0, stream>>>(PART, b3p, VAL);

    // ---- deformable gather ----
    gather_kernel<<<16384, blk, 0, stream>>>(VAL, awf, idxv, OUT0);

    // ---- output projection + LN + final projection ----
    gemm2<false><<<dim3(8, 32), blk, 0, stream>>>(OUT0, OPW, op_b, OUT1, 4096, 1024, 1024);
    ln_bf16_kernel<<<4096, blk, 0, stream>>>(OUT1, fln_g, fln_b, LNO);
    gemm2<false><<<dim3(8, 32), blk, 0, stream>>>(LNO, FINW, fin_b, out, 4096, 1024, 1024);
}